// Round 14
// baseline (592.703 us; speedup 1.0000x reference)
//
#include <hip/hip_runtime.h>
#include <math.h>

#define HW   4096
#define NCH  256
#define NB   4

constexpr float TEMP  = (float)(0.0001 * 5.0);
constexpr float INV_T = 1.0f / TEMP;
constexpr float EPSN  = 2.220446049250313e-16f;

typedef __attribute__((ext_vector_type(8))) _Float16 f16x8;
typedef __attribute__((ext_vector_type(4))) _Float16 f16x4;
typedef __attribute__((ext_vector_type(4))) float    f32x4;

// ---------------- workspace layout (in floats) ----------------
constexpr size_t OFF_YT    = 0;                                 // yf16: NB*HW*NCH f16
constexpr size_t OFF_YI    = OFF_YT    + (size_t)NB*HW*NCH;     // NB*3*HW
constexpr size_t OFF_MEAN  = OFF_YI    + (size_t)NB*3*HW;       // 2*NB*NCH
constexpr size_t OFF_RNORM = OFF_MEAN  + (size_t)2*NB*NCH;      // 2*NB*HW
constexpr size_t OFF_NSQP  = OFF_RNORM + (size_t)2*NB*HW;       // 2*NB*8*HW
constexpr size_t OFF_F     = OFF_NSQP  + (size_t)2*NB*8*HW;     // HW*HW (f32 f)
constexpr size_t OFF_YP    = OFF_F     + (size_t)HW*HW;         // region reused
constexpr size_t OFF_ROWP  = OFF_YP;                            // [32 ntile][7][HW]
constexpr size_t OFF_COLP  = OFF_YP + (size_t)32*7*HW;          // [32 mtile][1][HW] (max only)
constexpr size_t OFF_RMAX  = OFF_YP    + (size_t)8*NCH*HW;
constexpr size_t OFF_RSUM  = OFF_RMAX  + HW;
constexpr size_t OFF_CMAX  = OFF_RSUM  + HW;
constexpr size_t OFF_COORD = OFF_CMAX  + HW;                // NB*2*HW
constexpr size_t OFF_ATTN  = OFF_COORD + (size_t)NB*2*HW;   // NB*HW*3
constexpr size_t OFF_CYC   = OFF_ATTN  + (size_t)NB*HW*3;   // NB*3*HW
constexpr size_t OFF_CYCP  = OFF_CYC   + (size_t)NB*3*HW;   // 32*4*HW
constexpr size_t OFF_LOSSP = OFF_CYCP  + (size_t)32*4*HW;   // 1024
constexpr size_t OFF_F16   = OFF_LOSSP + 1024;              // 4 * 524288 floats

// ---------------- output layout (floats) ----------------
constexpr size_t OUT_Y    = 0;
constexpr size_t OUT_FLOW = (size_t)NB*NCH*HW;
constexpr size_t OUT_IMG  = OUT_FLOW + (size_t)NB*2*256*256;
constexpr size_t OUT_CYCO = OUT_IMG  + (size_t)NB*3*256*256;
constexpr size_t OUT_LOSS = OUT_CYCO + (size_t)NB*3*256*256;

__device__ __forceinline__ void gload16(const void* g, void* l) {
    __builtin_amdgcn_global_load_lds(
        (const __attribute__((address_space(1))) unsigned int*)g,
        (__attribute__((address_space(3))) unsigned int*)l, 16, 0, 0);
}

__global__ void mean_kernel(const float* __restrict__ xf, const float* __restrict__ yf,
                            float* __restrict__ means) {
    const float* src = (blockIdx.y == 0 ? xf : yf) + (size_t)blockIdx.x * HW;
    float s = 0.f;
    for (int i = threadIdx.x; i < HW; i += 256) s += src[i];
    __shared__ float red[256];
    red[threadIdx.x] = s; __syncthreads();
    for (int st = 128; st > 0; st >>= 1) {
        if (threadIdx.x < st) red[threadIdx.x] += red[threadIdx.x + st];
        __syncthreads();
    }
    if (threadIdx.x == 0) means[blockIdx.y * (NB*NCH) + blockIdx.x] = red[0] * (1.0f / HW);
}

__global__ void nsq_combine_kernel(const float* __restrict__ part, float* __restrict__ rnorms,
                                   int b) {
    int t = blockIdx.y;
    int m = blockIdx.x * 256 + threadIdx.x;
    const float* p = part + ((size_t)t*NB + b) * 8 * HW + m;
    float s = 0.f;
    for (int k = 0; k < 8; ++k) s += p[(size_t)k * HW];
    rnorms[((size_t)t*NB + b) * HW + m] = 1.0f / (sqrtf(s) + EPSN);
}

__global__ void ycast_kernel(const float* __restrict__ yf, _Float16* __restrict__ yf16) {
    size_t i = ((size_t)blockIdx.x * 256 + threadIdx.x) * 8;
    const float4* s = (const float4*)(yf + i);
    float4 v0 = s[0], v1 = s[1];
    f16x8 o;
    o[0]=(_Float16)v0.x; o[1]=(_Float16)v0.y; o[2]=(_Float16)v0.z; o[3]=(_Float16)v0.w;
    o[4]=(_Float16)v1.x; o[5]=(_Float16)v1.y; o[6]=(_Float16)v1.z; o[7]=(_Float16)v1.w;
    *(f16x8*)(yf16 + i) = o;
}

__global__ void prep_kernel(const float* __restrict__ xf, const float* __restrict__ yf,
                            const float* __restrict__ means,
                            _Float16* __restrict__ th, _Float16* __restrict__ tl,
                            _Float16* __restrict__ ph, _Float16* __restrict__ pl,
                            float* __restrict__ nsqp, int b) {
    __shared__ float tile[32][33];
    __shared__ float sqr[8][33];
    int t = blockIdx.z;
    int c0 = blockIdx.x * 32, m0 = blockIdx.y * 32;
    const float* src = (t == 0 ? xf : yf) + (size_t)b * NCH * HW;
    const float* mn  = means + t * (NB*NCH) + b * NCH;
    int tx = threadIdx.x & 31, ty = threadIdx.x >> 5;
    float sq = 0.f;
    for (int i = ty; i < 32; i += 8) {
        float v = src[(size_t)(c0 + i) * HW + m0 + tx] - mn[c0 + i];
        tile[i][tx] = v;
        sq += v * v;
    }
    sqr[ty][tx] = sq;
    __syncthreads();
    _Float16* H = (t == 0 ? th : ph);
    _Float16* L = (t == 0 ? tl : pl);
    for (int i = ty; i < 32; i += 8) {
        float v = tile[tx][i];
        _Float16 h = (_Float16)v;
        _Float16 l = (_Float16)(v - (float)h);
        H[(size_t)(m0 + i)*NCH + c0 + tx] = h;
        L[(size_t)(m0 + i)*NCH + c0 + tx] = l;
    }
    if (ty == 0) {
        float s = 0.f;
        #pragma unroll
        for (int k = 0; k < 8; ++k) s += sqr[k][tx];
        nsqp[(((size_t)t*NB + b) * 8 + blockIdx.x) * HW + m0 + tx] = s;
    }
}

__global__ void avgpool_kernel(const float* __restrict__ yimg, float* __restrict__ yi) {
    size_t idx = (size_t)blockIdx.x * 256 + threadIdx.x;
    int m  = (int)(idx & (HW - 1));
    int bc = (int)(idx >> 12);
    int h = m >> 6, w = m & 63;
    const float* p = yimg + (size_t)bc * 65536 + (size_t)(h*4) * 256 + w*4;
    float s = 0.f;
    #pragma unroll
    for (int dy = 0; dy < 4; ++dy) {
        #pragma unroll
        for (int dx = 0; dx < 4; ++dx) s += p[dy*256 + dx];
    }
    yi[idx] = s * (1.0f/16.0f);
}

// f^T accumulator GEMM: 128x128 tile, 8 waves (4 m-quarters x 2 n-halves), BK=32,
// 2-phase dbuf LDS for HI tiles only; LO fragments read direct from global (L2-hot).
// LDS dbuf = 32 KB -> 4 blocks/CU -> 32 waves/CU.
__global__ __launch_bounds__(512) void gemm_f_kernel(
        const _Float16* __restrict__ th, const _Float16* __restrict__ tl,
        const _Float16* __restrict__ ph, const _Float16* __restrict__ pl,
        const float* __restrict__ rnorms, const float* __restrict__ yi,
        float* __restrict__ f, float* __restrict__ rowp, float* __restrict__ colp,
        int b) {
    __shared__ char lds[2][2][8192];   // [dbuf][A-hi(phi), B-hi(theta)][128 rows x 32 k f16]
    int tid  = threadIdx.x;
    int lane = tid & 63;
    int w = tid >> 6;
    int wm = w >> 2;       // 0..1  n-half (A/phi)
    int wn = w & 3;        // 0..3  m-quarter (B/theta)
    int m0 = blockIdx.y * 128, n0 = blockIdx.x * 128;

    int o0 = tid * 16;
    int r0 = o0 >> 6, s0 = (o0 >> 4) & 3, g0 = s0 ^ ((r0 >> 1) & 3);
    size_t ga0 = (size_t)(n0 + r0)*NCH + g0*8;   // phi row (n)
    size_t gb0 = (size_t)(m0 + r0)*NCH + g0*8;   // theta row (m)

    int fra = wm*64 + (lane & 15);   // A fragment rows (n-local), +i*16, i<4
    int frb = wn*32 + (lane & 15);   // B fragment rows (m-local), +j*16, j<2
    int ks  = lane >> 4;

    // direct-global lo fragment bases (linear layout; swizzle round-trips)
    const _Float16* alg = pl + (size_t)(n0 + fra)*NCH + ks*8;
    const _Float16* blg = tl + (size_t)(m0 + frb)*NCH + ks*8;

    auto STAGE = [&](int buf, int k0) {
        gload16(ph + ga0 + k0, &lds[buf][0][o0]);
        gload16(th + gb0 + k0, &lds[buf][1][o0]);
    };

    f32x4 acc[4][2];
    #pragma unroll
    for (int i = 0; i < 4; ++i)
        #pragma unroll
        for (int j = 0; j < 2; ++j) acc[i][j] = (f32x4){0.f, 0.f, 0.f, 0.f};

    STAGE(0, 0);
    __syncthreads();
    int cur = 0;
    for (int kt = 0; kt < 8; ++kt) {
        int k0 = kt * 32;
        if (kt < 7) STAGE(cur ^ 1, k0 + 32);

        // lo fragments from global first (longest latency)
        f16x8 al[4], bl[2];
        #pragma unroll
        for (int i = 0; i < 4; ++i)
            al[i] = *(const f16x8*)(alg + (size_t)i*16*NCH + k0);
        #pragma unroll
        for (int j = 0; j < 2; ++j)
            bl[j] = *(const f16x8*)(blg + (size_t)j*16*NCH + k0);

        f16x8 ah[4], bh[2];
        #pragma unroll
        for (int i = 0; i < 4; ++i) {
            int rowa = fra + i*16;
            ah[i] = *(const f16x8*)&lds[cur][0][rowa*64 + ((ks ^ ((rowa >> 1) & 3)) << 4)];
        }
        #pragma unroll
        for (int j = 0; j < 2; ++j) {
            int rowb = frb + j*16;
            bh[j] = *(const f16x8*)&lds[cur][1][rowb*64 + ((ks ^ ((rowb >> 1) & 3)) << 4)];
        }
        __builtin_amdgcn_s_setprio(1);
        #pragma unroll
        for (int i = 0; i < 4; ++i)
            #pragma unroll
            for (int j = 0; j < 2; ++j) {
                acc[i][j] = __builtin_amdgcn_mfma_f32_16x16x32_f16(ah[i], bh[j], acc[i][j], 0, 0, 0);
                acc[i][j] = __builtin_amdgcn_mfma_f32_16x16x32_f16(ah[i], bl[j], acc[i][j], 0, 0, 0);
                acc[i][j] = __builtin_amdgcn_mfma_f32_16x16x32_f16(al[i], bh[j], acc[i][j], 0, 0, 0);
            }
        __builtin_amdgcn_s_setprio(0);
        __syncthreads();
        cur ^= 1;
    }

    // ---- scale in place: f[m][n] = accT * rnx[m] * rny[n] ----
    const float* rnx = rnorms + (size_t)b * HW;
    const float* rny = rnorms + (size_t)(NB + b) * HW;
    int mg[2];  float rxv[2];
    #pragma unroll
    for (int j = 0; j < 2; ++j) {
        mg[j] = m0 + wn*32 + j*16 + (lane & 15);
        rxv[j] = rnx[mg[j]];
    }
    int nl0 = wm*64 + (lane >> 4)*4;
    #pragma unroll
    for (int i = 0; i < 4; ++i)
        #pragma unroll
        for (int r = 0; r < 4; ++r) {
            float ry = rny[n0 + nl0 + i*16 + r];
            #pragma unroll
            for (int j = 0; j < 2; ++j) acc[i][j][r] *= rxv[j] * ry;
        }

    // ---- write f ----
    #pragma unroll
    for (int j = 0; j < 2; ++j)
        #pragma unroll
        for (int i = 0; i < 4; ++i)
            *(f32x4*)&f[(size_t)mg[j]*HW + n0 + nl0 + i*16] = acc[i][j];

    // ---- stats (LDS overlay after final loop barrier) ----
    float* S     = (float*)&lds[0][0][0];
    float* rowm  = S;          // [2 wm][128 m]
    float* sums6 = S + 256;    // [2 wm][128 m][6]
    float* colm  = S + 1792;   // [4 wn][128 n]

    #pragma unroll
    for (int j = 0; j < 2; ++j) {
        float v = acc[0][j][0];
        #pragma unroll
        for (int i = 0; i < 4; ++i)
            #pragma unroll
            for (int r = 0; r < 4; ++r) v = fmaxf(v, acc[i][j][r]);
        v = fmaxf(v, __shfl_xor(v, 16));
        v = fmaxf(v, __shfl_xor(v, 32));
        if (lane < 16) rowm[wm*128 + wn*32 + j*16 + lane] = v;
    }
    #pragma unroll
    for (int i = 0; i < 4; ++i)
        #pragma unroll
        for (int r = 0; r < 4; ++r) {
            float v = fmaxf(acc[i][0][r], acc[i][1][r]);
            #pragma unroll
            for (int d = 1; d < 16; d <<= 1) v = fmaxf(v, __shfl_xor(v, d));
            if ((lane & 15) == 0) colm[wn*128 + nl0 + i*16 + r] = v;
        }
    __syncthreads();

    float bm[2];
    #pragma unroll
    for (int j = 0; j < 2; ++j) {
        int ml = wn*32 + j*16 + (lane & 15);
        bm[j] = fmaxf(rowm[ml], rowm[128 + ml]);
    }
    float a6[2][6];
    #pragma unroll
    for (int j = 0; j < 2; ++j)
        #pragma unroll
        for (int q = 0; q < 6; ++q) a6[j][q] = 0.f;
    const float* yib = yi + (size_t)b * 3 * HW;
    #pragma unroll
    for (int i = 0; i < 4; ++i)
        #pragma unroll
        for (int r = 0; r < 4; ++r) {
            int ng = n0 + nl0 + i*16 + r;
            float xc = (float)(ng & 63), yc = (float)(ng >> 6);
            float y0 = yib[ng], y1 = yib[HW + ng], y2 = yib[2*HW + ng];
            #pragma unroll
            for (int j = 0; j < 2; ++j) {
                float e = __expf((acc[i][j][r] - bm[j]) * INV_T);
                a6[j][0] += e;      a6[j][1] += e*xc; a6[j][2] += e*yc;
                a6[j][3] += e*y0;   a6[j][4] += e*y1; a6[j][5] += e*y2;
            }
        }
    #pragma unroll
    for (int j = 0; j < 2; ++j)
        #pragma unroll
        for (int q = 0; q < 6; ++q) {
            float v = a6[j][q];
            v += __shfl_xor(v, 16);
            v += __shfl_xor(v, 32);
            if (lane < 16) sums6[(wm*128 + wn*32 + j*16 + lane)*6 + q] = v;
        }
    __syncthreads();

    if (tid < 128) {
        int ml = tid;
        float m2 = fmaxf(rowm[ml], rowm[128 + ml]);
        rowp[((size_t)blockIdx.x*7 + 0)*HW + m0 + ml] = m2;
        #pragma unroll
        for (int q = 0; q < 6; ++q)
            rowp[((size_t)blockIdx.x*7 + 1 + q)*HW + m0 + ml] =
                sums6[ml*6 + q] + sums6[(128 + ml)*6 + q];
    } else if (tid < 256) {
        int nl = tid - 128;
        float c2 = fmaxf(fmaxf(colm[nl], colm[128 + nl]),
                         fmaxf(colm[256 + nl], colm[384 + nl]));
        colp[(size_t)blockIdx.y*HW + n0 + nl] = c2;
    }
}

// merged combine: y==0 -> row stats; y==1 -> col max only
__global__ void rowcol_combine_kernel(const float* __restrict__ rowp,
        const float* __restrict__ colp,
        float* __restrict__ rmax, float* __restrict__ rsuminv,
        float* __restrict__ coords, float* __restrict__ attn,
        float* __restrict__ cmax, int b) {
    int idx = blockIdx.x * 256 + threadIdx.x;
    if (blockIdx.y == 0) {
        int m = idx;
        float gm = -3.0e38f;
        for (int t = 0; t < 32; ++t) gm = fmaxf(gm, rowp[((size_t)t*7)*HW + m]);
        float S=0, CX=0, CY=0, A0=0, A1=0, A2=0;
        for (int t = 0; t < 32; ++t) {
            const float* p = rowp + (size_t)t*7*HW + m;
            float wgt = __expf((p[0] - gm) * INV_T);
            S  += p[1*HW] * wgt; CX += p[2*HW] * wgt; CY += p[3*HW] * wgt;
            A0 += p[4*HW] * wgt; A1 += p[5*HW] * wgt; A2 += p[6*HW] * wgt;
        }
        float inv = 1.0f / S;
        rmax[m] = gm; rsuminv[m] = inv;
        coords[((size_t)b*2 + 0)*HW + m] = CX * inv;
        coords[((size_t)b*2 + 1)*HW + m] = CY * inv;
        attn[((size_t)b*HW + m)*3 + 0] = A0 * inv;
        attn[((size_t)b*HW + m)*3 + 1] = A1 * inv;
        attn[((size_t)b*HW + m)*3 + 2] = A2 * inv;
    } else {
        int n = idx;
        float gm = -3.0e38f;
        for (int t = 0; t < 32; ++t) gm = fmaxf(gm, colp[(size_t)t*HW + n]);
        cmax[n] = gm;
    }
}

// y partials: MFMA f16, split-K=4, tile 64m x 256c, 8 waves; f16 partial output.
__global__ __launch_bounds__(512) void gemm_y_kernel(const float* __restrict__ f,
        const float* __restrict__ rmax, const _Float16* __restrict__ yf16,
        _Float16* __restrict__ yph, int b) {
    __shared__ __align__(16) char ldsA[4096];
    __shared__ __align__(16) char ldsB[16384];
    int tid  = threadIdx.x;
    int lane = tid & 63;
    int w = tid >> 6, wm = w >> 2, wn = w & 3;
    int m0 = blockIdx.x * 64;
    int ks = blockIdx.y;
    const _Float16* Yb = yf16 + (size_t)b * NCH * HW;

    int ar = tid >> 3, kc = tid & 7;
    int aslot = kc >> 1, ahalf = kc & 1;
    int aoff = ar*64 + ((aslot ^ ((ar >> 1) & 3)) << 4) + ahalf*8;
    float arm = rmax[m0 + ar];
    const float* frow = f + (size_t)(m0 + ar)*HW + kc*4;

    int o0 = tid*16, o1 = o0 + 8192;
    int br0 = o0 >> 6, bs0 = (o0 >> 4) & 3, bg0 = bs0 ^ ((br0 >> 1) & 3);
    int br1 = o1 >> 6, bs1 = (o1 >> 4) & 3, bg1 = bs1 ^ ((br1 >> 1) & 3);
    size_t gb0 = (size_t)br0*HW + bg0*8;
    size_t gb1 = (size_t)br1*HW + bg1*8;

    int fra = wm*32 + (lane & 15);
    int frb = wn*64 + (lane & 15);
    int kslot = lane >> 4;

    f32x4 acc[2][4];
    #pragma unroll
    for (int i = 0; i < 2; ++i)
        #pragma unroll
        for (int j = 0; j < 4; ++j) acc[i][j] = (f32x4){0.f, 0.f, 0.f, 0.f};

    for (int k0 = ks*1024; k0 < ks*1024 + 1024; k0 += 32) {
        gload16(Yb + gb0 + k0, &ldsB[o0]);
        gload16(Yb + gb1 + k0, &ldsB[o1]);
        {
            float4 v = *(const float4*)(frow + k0);
            f16x4 pk;
            pk[0] = (_Float16)__expf((v.x - arm) * INV_T);
            pk[1] = (_Float16)__expf((v.y - arm) * INV_T);
            pk[2] = (_Float16)__expf((v.z - arm) * INV_T);
            pk[3] = (_Float16)__expf((v.w - arm) * INV_T);
            *(f16x4*)&ldsA[aoff] = pk;
        }
        __syncthreads();

        f16x8 af[2], bf[4];
        #pragma unroll
        for (int i = 0; i < 2; ++i) {
            int rowa = fra + i*16;
            af[i] = *(const f16x8*)&ldsA[rowa*64 + ((kslot ^ ((rowa >> 1) & 3)) << 4)];
        }
        #pragma unroll
        for (int j = 0; j < 4; ++j) {
            int rowb = frb + j*16;
            bf[j] = *(const f16x8*)&ldsB[rowb*64 + ((kslot ^ ((rowb >> 1) & 3)) << 4)];
        }
        __builtin_amdgcn_s_setprio(1);
        #pragma unroll
        for (int i = 0; i < 2; ++i)
            #pragma unroll
            for (int j = 0; j < 4; ++j)
                acc[i][j] = __builtin_amdgcn_mfma_f32_16x16x32_f16(af[i], bf[j], acc[i][j], 0, 0, 0);
        __builtin_amdgcn_s_setprio(0);
        __syncthreads();
    }

    #pragma unroll
    for (int i = 0; i < 2; ++i) {
        int m = m0 + wm*32 + i*16 + (lane >> 4) * 4;
        #pragma unroll
        for (int j = 0; j < 4; ++j) {
            int c = wn*64 + j*16 + (lane & 15);
            f16x4 v;
            #pragma unroll
            for (int r = 0; r < 4; ++r) v[r] = (_Float16)acc[i][j][r];
            *(f16x4*)(yph + ((size_t)ks*NCH + c)*HW + m) = v;
        }
    }
}

__global__ void ycombine_kernel(const _Float16* __restrict__ yph, const float* __restrict__ rsuminv,
                                float* __restrict__ out, int b) {
    size_t idx = (size_t)blockIdx.x * 256 + threadIdx.x;
    int m = (int)(idx & (HW - 1));
    float s = 0.f;
    #pragma unroll
    for (int k = 0; k < 4; ++k) s += (float)yph[(size_t)k*NCH*HW + idx];
    out[OUT_Y + (size_t)b*NCH*HW + idx] = s * rsuminv[m];
}

__global__ __launch_bounds__(256) void cyc_partial_kernel(const float* __restrict__ f,
        const float* __restrict__ cmax, const float* __restrict__ attn,
        float* __restrict__ part, int b) {
    __shared__ float at[128*3];
    int i  = blockIdx.x * 256 + threadIdx.x;
    int j0 = blockIdx.y * 128;
    for (int k = threadIdx.x; k < 384; k += 256)
        at[k] = attn[((size_t)b*HW + j0)*3 + k];
    __syncthreads();
    float cm = cmax[i];
    float a0=0, a1=0, a2=0, a3=0;
    for (int jj = 0; jj < 128; ++jj) {
        float e = __expf((f[(size_t)(j0+jj)*HW + i] - cm) * INV_T);
        a0 = fmaf(e, at[jj*3+0], a0);
        a1 = fmaf(e, at[jj*3+1], a1);
        a2 = fmaf(e, at[jj*3+2], a2);
        a3 += e;
    }
    part[((size_t)blockIdx.y*4 + 0)*HW + i] = a0;
    part[((size_t)blockIdx.y*4 + 1)*HW + i] = a1;
    part[((size_t)blockIdx.y*4 + 2)*HW + i] = a2;
    part[((size_t)blockIdx.y*4 + 3)*HW + i] = a3;
}

__global__ void cyc_combine_kernel(const float* __restrict__ part,
                                   float* __restrict__ cyc, int b) {
    int i = blockIdx.x * 256 + threadIdx.x;
    int c = blockIdx.y;
    float s = 0.f, den = 0.f;
    for (int k = 0; k < 32; ++k) {
        s   += part[((size_t)k*4 + c)*HW + i];
        den += part[((size_t)k*4 + 3)*HW + i];
    }
    cyc[((size_t)b*3 + c)*HW + i] = s / den;
}

__global__ void flow_kernel(const float* __restrict__ coords, float* __restrict__ out) {
    size_t idx = (size_t)blockIdx.x * 256 + threadIdx.x;
    int x4 = (int)(idx & 255);
    int y4 = (int)((idx >> 8) & 255);
    int ch = (int)((idx >> 16) & 1);
    int b  = (int)(idx >> 17);
    int w = x4 >> 2, h = y4 >> 2;
    int m = h*64 + w;
    float c1 = coords[((size_t)b*2 + ch)*HW + m];
    float c0 = (ch == 0) ? (float)w : (float)h;
    out[OUT_FLOW + idx] = c1 - c0;
}

__global__ void imgout_kernel(const float* __restrict__ attn, const float* __restrict__ cyc,
                              float* __restrict__ out) {
    size_t idx = (size_t)blockIdx.x * 256 + threadIdx.x;
    int x4 = (int)(idx & 255);
    int y4 = (int)((idx >> 8) & 255);
    int rest = (int)(idx >> 16);
    int ch = rest % 3, b = rest / 3;
    int m = (y4 >> 2)*64 + (x4 >> 2);
    out[OUT_IMG  + idx] = attn[((size_t)b*HW + m)*3 + ch];
    out[OUT_CYCO + idx] = cyc[((size_t)b*3 + ch)*HW + m];
}

__global__ void loss_partial_kernel(const float* __restrict__ xf, const float* __restrict__ yf,
                                    const float* __restrict__ means, const float* __restrict__ rnorms,
                                    float* __restrict__ part) {
    __shared__ float red[256];
    size_t base = (size_t)blockIdx.x * 4096;
    float s = 0.f;
    for (int k = 0; k < 16; ++k) {
        size_t id = base + (size_t)k*256 + threadIdx.x;
        int m  = (int)(id & (HW - 1));
        int bc = (int)(id >> 12);
        int b  = bc >> 8;
        float th = (xf[id] - means[bc])          * rnorms[(size_t)b*HW + m];
        float ph = (yf[id] - means[NB*NCH + bc]) * rnorms[(size_t)(NB + b)*HW + m];
        s += fabsf(th - ph);
    }
    red[threadIdx.x] = s; __syncthreads();
    for (int st = 128; st > 0; st >>= 1) {
        if (threadIdx.x < st) red[threadIdx.x] += red[threadIdx.x + st];
        __syncthreads();
    }
    if (threadIdx.x == 0) part[blockIdx.x] = red[0];
}

__global__ void loss_final_kernel(const float* __restrict__ part, float* __restrict__ out) {
    __shared__ float red[256];
    float s = 0.f;
    for (int k = threadIdx.x; k < 1024; k += 256) s += part[k];
    red[threadIdx.x] = s; __syncthreads();
    for (int st = 128; st > 0; st >>= 1) {
        if (threadIdx.x < st) red[threadIdx.x] += red[threadIdx.x + st];
        __syncthreads();
    }
    if (threadIdx.x == 0) out[OUT_LOSS] = red[0] * (1.0f / 4194304.0f);
}

extern "C" void kernel_launch(void* const* d_in, const int* in_sizes, int n_in,
                              void* d_out, int out_size, void* d_ws, size_t ws_size,
                              hipStream_t stream) {
    (void)in_sizes; (void)n_in; (void)out_size; (void)ws_size;
    const float* xf   = (const float*)d_in[0];
    const float* yf   = (const float*)d_in[1];
    const float* yimg = (const float*)d_in[2];
    float* out = (float*)d_out;
    float* ws  = (float*)d_ws;

    _Float16* yf16 = (_Float16*)(ws + OFF_YT);
    float* yi      = ws + OFF_YI;
    float* means   = ws + OFF_MEAN;
    float* rnorms  = ws + OFF_RNORM;
    float* nsqp    = ws + OFF_NSQP;
    float* fbuf    = ws + OFF_F;
    _Float16* yph  = (_Float16*)(ws + OFF_YP);
    float* rowp    = ws + OFF_ROWP;
    float* colp    = ws + OFF_COLP;
    float* rmax    = ws + OFF_RMAX;
    float* rsuminv = ws + OFF_RSUM;
    float* cmax    = ws + OFF_CMAX;
    float* coords  = ws + OFF_COORD;
    float* attn    = ws + OFF_ATTN;
    float* cyc     = ws + OFF_CYC;
    float* cycp    = ws + OFF_CYCP;
    float* lossp   = ws + OFF_LOSSP;
    _Float16* th = (_Float16*)(ws + OFF_F16);
    _Float16* tl = th + (size_t)HW*NCH;
    _Float16* ph = tl + (size_t)HW*NCH;
    _Float16* pl = ph + (size_t)HW*NCH;

    mean_kernel        <<<dim3(NB*NCH, 2),   256, 0, stream>>>(xf, yf, means);
    ycast_kernel       <<<2048,              256, 0, stream>>>(yf, yf16);
    avgpool_kernel     <<<NB*3*HW/256,       256, 0, stream>>>(yimg, yi);

    for (int b = 0; b < NB; ++b) {
        prep_kernel          <<<dim3(8, 128, 2), 256, 0, stream>>>(xf, yf, means, th, tl, ph, pl,
                                                                   nsqp, b);
        nsq_combine_kernel   <<<dim3(16, 2),     256, 0, stream>>>(nsqp, rnorms, b);
        gemm_f_kernel        <<<dim3(32, 32),    512, 0, stream>>>(th, tl, ph, pl, rnorms, yi,
                                                                   fbuf, rowp, colp, b);
        rowcol_combine_kernel<<<dim3(16, 2),     256, 0, stream>>>(rowp, colp, rmax, rsuminv,
                                                                   coords, attn, cmax, b);
        gemm_y_kernel        <<<dim3(64, 4),     512, 0, stream>>>(fbuf, rmax, yf16, yph, b);
        ycombine_kernel      <<<NCH*HW/256,      256, 0, stream>>>(yph, rsuminv, out, b);
        cyc_partial_kernel   <<<dim3(16, 32),    256, 0, stream>>>(fbuf, cmax, attn, cycp, b);
        cyc_combine_kernel   <<<dim3(16, 3),     256, 0, stream>>>(cycp, cyc, b);
    }

    flow_kernel        <<<NB*2*65536/256, 256, 0, stream>>>(coords, out);
    imgout_kernel      <<<NB*3*65536/256, 256, 0, stream>>>(attn, cyc, out);
    loss_partial_kernel<<<1024,           256, 0, stream>>>(xf, yf, means, rnorms, lossp);
    loss_final_kernel  <<<1,              256, 0, stream>>>(lossp, out);
}

// Round 15
// 515.940 us; speedup vs baseline: 1.1488x; 1.1488x over previous
//
#include <hip/hip_runtime.h>
#include <math.h>

#define HW   4096
#define NCH  256
#define NB   4

constexpr float TEMP  = (float)(0.0001 * 5.0);
constexpr float INV_T = 1.0f / TEMP;
constexpr float EPSN  = 2.220446049250313e-16f;

typedef __attribute__((ext_vector_type(8))) _Float16 f16x8;
typedef __attribute__((ext_vector_type(4))) _Float16 f16x4;
typedef __attribute__((ext_vector_type(4))) float    f32x4;

// ---------------- workspace layout (in floats) ----------------
constexpr size_t OFF_YT    = 0;                                 // yf16: NB*HW*NCH f16
constexpr size_t OFF_YI    = OFF_YT    + (size_t)NB*HW*NCH;     // NB*3*HW
constexpr size_t OFF_MEAN  = OFF_YI    + (size_t)NB*3*HW;       // 2*NB*NCH
constexpr size_t OFF_RNORM = OFF_MEAN  + (size_t)2*NB*NCH;      // 2*NB*HW
constexpr size_t OFF_NSQP  = OFF_RNORM + (size_t)2*NB*HW;       // 2*NB*8*HW
constexpr size_t OFF_F     = OFF_NSQP  + (size_t)2*NB*8*HW;     // HW*HW (f32 f)
constexpr size_t OFF_YP    = OFF_F     + (size_t)HW*HW;         // region reused
constexpr size_t OFF_ROWP  = OFF_YP;                            // [32 ntile][7][HW]
constexpr size_t OFF_COLP  = OFF_YP + (size_t)32*7*HW;          // [32 mtile][1][HW] (max only)
constexpr size_t OFF_RMAX  = OFF_YP    + (size_t)8*NCH*HW;
constexpr size_t OFF_RSUM  = OFF_RMAX  + HW;
constexpr size_t OFF_CMAX  = OFF_RSUM  + HW;
constexpr size_t OFF_COORD = OFF_CMAX  + HW;                // NB*2*HW
constexpr size_t OFF_ATTN  = OFF_COORD + (size_t)NB*2*HW;   // NB*HW*3
constexpr size_t OFF_CYC   = OFF_ATTN  + (size_t)NB*HW*3;   // NB*3*HW
constexpr size_t OFF_CYCP  = OFF_CYC   + (size_t)NB*3*HW;   // 32*4*HW
constexpr size_t OFF_LOSSP = OFF_CYCP  + (size_t)32*4*HW;   // 1024
constexpr size_t OFF_F16   = OFF_LOSSP + 1024;              // 4 * 524288 floats

// ---------------- output layout (floats) ----------------
constexpr size_t OUT_Y    = 0;
constexpr size_t OUT_FLOW = (size_t)NB*NCH*HW;
constexpr size_t OUT_IMG  = OUT_FLOW + (size_t)NB*2*256*256;
constexpr size_t OUT_CYCO = OUT_IMG  + (size_t)NB*3*256*256;
constexpr size_t OUT_LOSS = OUT_CYCO + (size_t)NB*3*256*256;

__device__ __forceinline__ void gload16(const void* g, void* l) {
    __builtin_amdgcn_global_load_lds(
        (const __attribute__((address_space(1))) unsigned int*)g,
        (__attribute__((address_space(3))) unsigned int*)l, 16, 0, 0);
}

__global__ void mean_kernel(const float* __restrict__ xf, const float* __restrict__ yf,
                            float* __restrict__ means) {
    const float* src = (blockIdx.y == 0 ? xf : yf) + (size_t)blockIdx.x * HW;
    float s = 0.f;
    for (int i = threadIdx.x; i < HW; i += 256) s += src[i];
    __shared__ float red[256];
    red[threadIdx.x] = s; __syncthreads();
    for (int st = 128; st > 0; st >>= 1) {
        if (threadIdx.x < st) red[threadIdx.x] += red[threadIdx.x + st];
        __syncthreads();
    }
    if (threadIdx.x == 0) means[blockIdx.y * (NB*NCH) + blockIdx.x] = red[0] * (1.0f / HW);
}

__global__ void nsq_combine_kernel(const float* __restrict__ part, float* __restrict__ rnorms,
                                   int b) {
    int t = blockIdx.y;
    int m = blockIdx.x * 256 + threadIdx.x;
    const float* p = part + ((size_t)t*NB + b) * 8 * HW + m;
    float s = 0.f;
    for (int k = 0; k < 8; ++k) s += p[(size_t)k * HW];
    rnorms[((size_t)t*NB + b) * HW + m] = 1.0f / (sqrtf(s) + EPSN);
}

__global__ void ycast_kernel(const float* __restrict__ yf, _Float16* __restrict__ yf16) {
    size_t i = ((size_t)blockIdx.x * 256 + threadIdx.x) * 8;
    const float4* s = (const float4*)(yf + i);
    float4 v0 = s[0], v1 = s[1];
    f16x8 o;
    o[0]=(_Float16)v0.x; o[1]=(_Float16)v0.y; o[2]=(_Float16)v0.z; o[3]=(_Float16)v0.w;
    o[4]=(_Float16)v1.x; o[5]=(_Float16)v1.y; o[6]=(_Float16)v1.z; o[7]=(_Float16)v1.w;
    *(f16x8*)(yf16 + i) = o;
}

__global__ void prep_kernel(const float* __restrict__ xf, const float* __restrict__ yf,
                            const float* __restrict__ means,
                            _Float16* __restrict__ th, _Float16* __restrict__ tl,
                            _Float16* __restrict__ ph, _Float16* __restrict__ pl,
                            float* __restrict__ nsqp, int b) {
    __shared__ float tile[32][33];
    __shared__ float sqr[8][33];
    int t = blockIdx.z;
    int c0 = blockIdx.x * 32, m0 = blockIdx.y * 32;
    const float* src = (t == 0 ? xf : yf) + (size_t)b * NCH * HW;
    const float* mn  = means + t * (NB*NCH) + b * NCH;
    int tx = threadIdx.x & 31, ty = threadIdx.x >> 5;
    float sq = 0.f;
    for (int i = ty; i < 32; i += 8) {
        float v = src[(size_t)(c0 + i) * HW + m0 + tx] - mn[c0 + i];
        tile[i][tx] = v;
        sq += v * v;
    }
    sqr[ty][tx] = sq;
    __syncthreads();
    _Float16* H = (t == 0 ? th : ph);
    _Float16* L = (t == 0 ? tl : pl);
    for (int i = ty; i < 32; i += 8) {
        float v = tile[tx][i];
        _Float16 h = (_Float16)v;
        _Float16 l = (_Float16)(v - (float)h);
        H[(size_t)(m0 + i)*NCH + c0 + tx] = h;
        L[(size_t)(m0 + i)*NCH + c0 + tx] = l;
    }
    if (ty == 0) {
        float s = 0.f;
        #pragma unroll
        for (int k = 0; k < 8; ++k) s += sqr[k][tx];
        nsqp[(((size_t)t*NB + b) * 8 + blockIdx.x) * HW + m0 + tx] = s;
    }
}

__global__ void avgpool_kernel(const float* __restrict__ yimg, float* __restrict__ yi) {
    size_t idx = (size_t)blockIdx.x * 256 + threadIdx.x;
    int m  = (int)(idx & (HW - 1));
    int bc = (int)(idx >> 12);
    int h = m >> 6, w = m & 63;
    const float* p = yimg + (size_t)bc * 65536 + (size_t)(h*4) * 256 + w*4;
    float s = 0.f;
    #pragma unroll
    for (int dy = 0; dy < 4; ++dy) {
        #pragma unroll
        for (int dx = 0; dx < 4; ++dx) s += p[dy*256 + dx];
    }
    yi[idx] = s * (1.0f/16.0f);
}

// f^T accumulator GEMM (R13-proven best): 128x128 tile, 8 waves (4 m-quarters x
// 2 n-halves), BK=32, 2-phase dbuf LDS (all 4 arrays). Row max + 6 exp row sums;
// col MAX only.
__global__ __launch_bounds__(512) void gemm_f_kernel(
        const _Float16* __restrict__ th, const _Float16* __restrict__ tl,
        const _Float16* __restrict__ ph, const _Float16* __restrict__ pl,
        const float* __restrict__ rnorms, const float* __restrict__ yi,
        float* __restrict__ f, float* __restrict__ rowp, float* __restrict__ colp,
        int b) {
    __shared__ char lds[2][4][8192];
    int tid  = threadIdx.x;
    int lane = tid & 63;
    int w = tid >> 6;
    int wm = w >> 2;       // 0..1  n-half (A/phi)
    int wn = w & 3;        // 0..3  m-quarter (B/theta)
    int m0 = blockIdx.y * 128, n0 = blockIdx.x * 128;

    int o0 = tid * 16;
    int r0 = o0 >> 6, s0 = (o0 >> 4) & 3, g0 = s0 ^ ((r0 >> 1) & 3);
    size_t ga0 = (size_t)(n0 + r0)*NCH + g0*8;   // phi row (n)
    size_t gb0 = (size_t)(m0 + r0)*NCH + g0*8;   // theta row (m)

    int fra = wm*64 + (lane & 15);   // A fragment rows (n-local), +i*16, i<4
    int frb = wn*32 + (lane & 15);   // B fragment rows (m-local), +j*16, j<2
    int ks  = lane >> 4;

    auto STAGE = [&](int buf, int k0) {
        gload16(ph + ga0 + k0, &lds[buf][0][o0]);
        gload16(pl + ga0 + k0, &lds[buf][1][o0]);
        gload16(th + gb0 + k0, &lds[buf][2][o0]);
        gload16(tl + gb0 + k0, &lds[buf][3][o0]);
    };

    f32x4 acc[4][2];
    #pragma unroll
    for (int i = 0; i < 4; ++i)
        #pragma unroll
        for (int j = 0; j < 2; ++j) acc[i][j] = (f32x4){0.f, 0.f, 0.f, 0.f};

    STAGE(0, 0);
    __syncthreads();
    int cur = 0;
    for (int kt = 0; kt < 8; ++kt) {
        if (kt < 7) STAGE(cur ^ 1, (kt + 1) * 32);

        f16x8 ah[4], al[4], bh[2], bl[2];
        #pragma unroll
        for (int i = 0; i < 4; ++i) {
            int rowa = fra + i*16;
            int offa = rowa*64 + ((ks ^ ((rowa >> 1) & 3)) << 4);
            ah[i] = *(const f16x8*)&lds[cur][0][offa];
            al[i] = *(const f16x8*)&lds[cur][1][offa];
        }
        #pragma unroll
        for (int j = 0; j < 2; ++j) {
            int rowb = frb + j*16;
            int offb = rowb*64 + ((ks ^ ((rowb >> 1) & 3)) << 4);
            bh[j] = *(const f16x8*)&lds[cur][2][offb];
            bl[j] = *(const f16x8*)&lds[cur][3][offb];
        }
        __builtin_amdgcn_s_setprio(1);
        #pragma unroll
        for (int i = 0; i < 4; ++i)
            #pragma unroll
            for (int j = 0; j < 2; ++j) {
                acc[i][j] = __builtin_amdgcn_mfma_f32_16x16x32_f16(ah[i], bh[j], acc[i][j], 0, 0, 0);
                acc[i][j] = __builtin_amdgcn_mfma_f32_16x16x32_f16(ah[i], bl[j], acc[i][j], 0, 0, 0);
                acc[i][j] = __builtin_amdgcn_mfma_f32_16x16x32_f16(al[i], bh[j], acc[i][j], 0, 0, 0);
            }
        __builtin_amdgcn_s_setprio(0);
        __syncthreads();
        cur ^= 1;
    }

    // ---- scale in place: f[m][n] = accT * rnx[m] * rny[n] ----
    const float* rnx = rnorms + (size_t)b * HW;
    const float* rny = rnorms + (size_t)(NB + b) * HW;
    int mg[2];  float rxv[2];
    #pragma unroll
    for (int j = 0; j < 2; ++j) {
        mg[j] = m0 + wn*32 + j*16 + (lane & 15);
        rxv[j] = rnx[mg[j]];
    }
    int nl0 = wm*64 + (lane >> 4)*4;
    #pragma unroll
    for (int i = 0; i < 4; ++i)
        #pragma unroll
        for (int r = 0; r < 4; ++r) {
            float ry = rny[n0 + nl0 + i*16 + r];
            #pragma unroll
            for (int j = 0; j < 2; ++j) acc[i][j][r] *= rxv[j] * ry;
        }

    // ---- write f ----
    #pragma unroll
    for (int j = 0; j < 2; ++j)
        #pragma unroll
        for (int i = 0; i < 4; ++i)
            *(f32x4*)&f[(size_t)mg[j]*HW + n0 + nl0 + i*16] = acc[i][j];

    // ---- stats ----
    float* S     = (float*)&lds[0][0][0];
    float* rowm  = S;          // [2 wm][128 m]
    float* sums6 = S + 256;    // [2 wm][128 m][6]
    float* colm  = S + 1792;   // [4 wn][128 n]

    #pragma unroll
    for (int j = 0; j < 2; ++j) {
        float v = acc[0][j][0];
        #pragma unroll
        for (int i = 0; i < 4; ++i)
            #pragma unroll
            for (int r = 0; r < 4; ++r) v = fmaxf(v, acc[i][j][r]);
        v = fmaxf(v, __shfl_xor(v, 16));
        v = fmaxf(v, __shfl_xor(v, 32));
        if (lane < 16) rowm[wm*128 + wn*32 + j*16 + lane] = v;
    }
    #pragma unroll
    for (int i = 0; i < 4; ++i)
        #pragma unroll
        for (int r = 0; r < 4; ++r) {
            float v = fmaxf(acc[i][0][r], acc[i][1][r]);
            #pragma unroll
            for (int d = 1; d < 16; d <<= 1) v = fmaxf(v, __shfl_xor(v, d));
            if ((lane & 15) == 0) colm[wn*128 + nl0 + i*16 + r] = v;
        }
    __syncthreads();

    float bm[2];
    #pragma unroll
    for (int j = 0; j < 2; ++j) {
        int ml = wn*32 + j*16 + (lane & 15);
        bm[j] = fmaxf(rowm[ml], rowm[128 + ml]);
    }
    float a6[2][6];
    #pragma unroll
    for (int j = 0; j < 2; ++j)
        #pragma unroll
        for (int q = 0; q < 6; ++q) a6[j][q] = 0.f;
    const float* yib = yi + (size_t)b * 3 * HW;
    #pragma unroll
    for (int i = 0; i < 4; ++i)
        #pragma unroll
        for (int r = 0; r < 4; ++r) {
            int ng = n0 + nl0 + i*16 + r;
            float xc = (float)(ng & 63), yc = (float)(ng >> 6);
            float y0 = yib[ng], y1 = yib[HW + ng], y2 = yib[2*HW + ng];
            #pragma unroll
            for (int j = 0; j < 2; ++j) {
                float e = __expf((acc[i][j][r] - bm[j]) * INV_T);
                a6[j][0] += e;      a6[j][1] += e*xc; a6[j][2] += e*yc;
                a6[j][3] += e*y0;   a6[j][4] += e*y1; a6[j][5] += e*y2;
            }
        }
    #pragma unroll
    for (int j = 0; j < 2; ++j)
        #pragma unroll
        for (int q = 0; q < 6; ++q) {
            float v = a6[j][q];
            v += __shfl_xor(v, 16);
            v += __shfl_xor(v, 32);
            if (lane < 16) sums6[(wm*128 + wn*32 + j*16 + lane)*6 + q] = v;
        }
    __syncthreads();

    if (tid < 128) {
        int ml = tid;
        float m2 = fmaxf(rowm[ml], rowm[128 + ml]);
        rowp[((size_t)blockIdx.x*7 + 0)*HW + m0 + ml] = m2;
        #pragma unroll
        for (int q = 0; q < 6; ++q)
            rowp[((size_t)blockIdx.x*7 + 1 + q)*HW + m0 + ml] =
                sums6[ml*6 + q] + sums6[(128 + ml)*6 + q];
    } else if (tid < 256) {
        int nl = tid - 128;
        float c2 = fmaxf(fmaxf(colm[nl], colm[128 + nl]),
                         fmaxf(colm[256 + nl], colm[384 + nl]));
        colp[(size_t)blockIdx.y*HW + n0 + nl] = c2;
    }
}

// merged combine: y==0 -> row stats; y==1 -> col max only
__global__ void rowcol_combine_kernel(const float* __restrict__ rowp,
        const float* __restrict__ colp,
        float* __restrict__ rmax, float* __restrict__ rsuminv,
        float* __restrict__ coords, float* __restrict__ attn,
        float* __restrict__ cmax, int b) {
    int idx = blockIdx.x * 256 + threadIdx.x;
    if (blockIdx.y == 0) {
        int m = idx;
        float gm = -3.0e38f;
        for (int t = 0; t < 32; ++t) gm = fmaxf(gm, rowp[((size_t)t*7)*HW + m]);
        float S=0, CX=0, CY=0, A0=0, A1=0, A2=0;
        for (int t = 0; t < 32; ++t) {
            const float* p = rowp + (size_t)t*7*HW + m;
            float wgt = __expf((p[0] - gm) * INV_T);
            S  += p[1*HW] * wgt; CX += p[2*HW] * wgt; CY += p[3*HW] * wgt;
            A0 += p[4*HW] * wgt; A1 += p[5*HW] * wgt; A2 += p[6*HW] * wgt;
        }
        float inv = 1.0f / S;
        rmax[m] = gm; rsuminv[m] = inv;
        coords[((size_t)b*2 + 0)*HW + m] = CX * inv;
        coords[((size_t)b*2 + 1)*HW + m] = CY * inv;
        attn[((size_t)b*HW + m)*3 + 0] = A0 * inv;
        attn[((size_t)b*HW + m)*3 + 1] = A1 * inv;
        attn[((size_t)b*HW + m)*3 + 2] = A2 * inv;
    } else {
        int n = idx;
        float gm = -3.0e38f;
        for (int t = 0; t < 32; ++t) gm = fmaxf(gm, colp[(size_t)t*HW + n]);
        cmax[n] = gm;
    }
}

// y partials: MFMA f16, split-K=4, tile 64m x 256c, 8 waves; f16 partial output.
__global__ __launch_bounds__(512) void gemm_y_kernel(const float* __restrict__ f,
        const float* __restrict__ rmax, const _Float16* __restrict__ yf16,
        _Float16* __restrict__ yph, int b) {
    __shared__ __align__(16) char ldsA[4096];
    __shared__ __align__(16) char ldsB[16384];
    int tid  = threadIdx.x;
    int lane = tid & 63;
    int w = tid >> 6, wm = w >> 2, wn = w & 3;
    int m0 = blockIdx.x * 64;
    int ks = blockIdx.y;
    const _Float16* Yb = yf16 + (size_t)b * NCH * HW;

    int ar = tid >> 3, kc = tid & 7;
    int aslot = kc >> 1, ahalf = kc & 1;
    int aoff = ar*64 + ((aslot ^ ((ar >> 1) & 3)) << 4) + ahalf*8;
    float arm = rmax[m0 + ar];
    const float* frow = f + (size_t)(m0 + ar)*HW + kc*4;

    int o0 = tid*16, o1 = o0 + 8192;
    int br0 = o0 >> 6, bs0 = (o0 >> 4) & 3, bg0 = bs0 ^ ((br0 >> 1) & 3);
    int br1 = o1 >> 6, bs1 = (o1 >> 4) & 3, bg1 = bs1 ^ ((br1 >> 1) & 3);
    size_t gb0 = (size_t)br0*HW + bg0*8;
    size_t gb1 = (size_t)br1*HW + bg1*8;

    int fra = wm*32 + (lane & 15);
    int frb = wn*64 + (lane & 15);
    int kslot = lane >> 4;

    f32x4 acc[2][4];
    #pragma unroll
    for (int i = 0; i < 2; ++i)
        #pragma unroll
        for (int j = 0; j < 4; ++j) acc[i][j] = (f32x4){0.f, 0.f, 0.f, 0.f};

    for (int k0 = ks*1024; k0 < ks*1024 + 1024; k0 += 32) {
        gload16(Yb + gb0 + k0, &ldsB[o0]);
        gload16(Yb + gb1 + k0, &ldsB[o1]);
        {
            float4 v = *(const float4*)(frow + k0);
            f16x4 pk;
            pk[0] = (_Float16)__expf((v.x - arm) * INV_T);
            pk[1] = (_Float16)__expf((v.y - arm) * INV_T);
            pk[2] = (_Float16)__expf((v.z - arm) * INV_T);
            pk[3] = (_Float16)__expf((v.w - arm) * INV_T);
            *(f16x4*)&ldsA[aoff] = pk;
        }
        __syncthreads();

        f16x8 af[2], bf[4];
        #pragma unroll
        for (int i = 0; i < 2; ++i) {
            int rowa = fra + i*16;
            af[i] = *(const f16x8*)&ldsA[rowa*64 + ((kslot ^ ((rowa >> 1) & 3)) << 4)];
        }
        #pragma unroll
        for (int j = 0; j < 4; ++j) {
            int rowb = frb + j*16;
            bf[j] = *(const f16x8*)&ldsB[rowb*64 + ((kslot ^ ((rowb >> 1) & 3)) << 4)];
        }
        __builtin_amdgcn_s_setprio(1);
        #pragma unroll
        for (int i = 0; i < 2; ++i)
            #pragma unroll
            for (int j = 0; j < 4; ++j)
                acc[i][j] = __builtin_amdgcn_mfma_f32_16x16x32_f16(af[i], bf[j], acc[i][j], 0, 0, 0);
        __builtin_amdgcn_s_setprio(0);
        __syncthreads();
    }

    #pragma unroll
    for (int i = 0; i < 2; ++i) {
        int m = m0 + wm*32 + i*16 + (lane >> 4) * 4;
        #pragma unroll
        for (int j = 0; j < 4; ++j) {
            int c = wn*64 + j*16 + (lane & 15);
            f16x4 v;
            #pragma unroll
            for (int r = 0; r < 4; ++r) v[r] = (_Float16)acc[i][j][r];
            *(f16x4*)(yph + ((size_t)ks*NCH + c)*HW + m) = v;
        }
    }
}

__global__ void ycombine_kernel(const _Float16* __restrict__ yph, const float* __restrict__ rsuminv,
                                float* __restrict__ out, int b) {
    size_t idx = (size_t)blockIdx.x * 256 + threadIdx.x;
    int m = (int)(idx & (HW - 1));
    float s = 0.f;
    #pragma unroll
    for (int k = 0; k < 4; ++k) s += (float)yph[(size_t)k*NCH*HW + idx];
    out[OUT_Y + (size_t)b*NCH*HW + idx] = s * rsuminv[m];
}

__global__ __launch_bounds__(256) void cyc_partial_kernel(const float* __restrict__ f,
        const float* __restrict__ cmax, const float* __restrict__ attn,
        float* __restrict__ part, int b) {
    __shared__ float at[128*3];
    int i  = blockIdx.x * 256 + threadIdx.x;
    int j0 = blockIdx.y * 128;
    for (int k = threadIdx.x; k < 384; k += 256)
        at[k] = attn[((size_t)b*HW + j0)*3 + k];
    __syncthreads();
    float cm = cmax[i];
    float a0=0, a1=0, a2=0, a3=0;
    for (int jj = 0; jj < 128; ++jj) {
        float e = __expf((f[(size_t)(j0+jj)*HW + i] - cm) * INV_T);
        a0 = fmaf(e, at[jj*3+0], a0);
        a1 = fmaf(e, at[jj*3+1], a1);
        a2 = fmaf(e, at[jj*3+2], a2);
        a3 += e;
    }
    part[((size_t)blockIdx.y*4 + 0)*HW + i] = a0;
    part[((size_t)blockIdx.y*4 + 1)*HW + i] = a1;
    part[((size_t)blockIdx.y*4 + 2)*HW + i] = a2;
    part[((size_t)blockIdx.y*4 + 3)*HW + i] = a3;
}

__global__ void cyc_combine_kernel(const float* __restrict__ part,
                                   float* __restrict__ cyc, int b) {
    int i = blockIdx.x * 256 + threadIdx.x;
    int c = blockIdx.y;
    float s = 0.f, den = 0.f;
    for (int k = 0; k < 32; ++k) {
        s   += part[((size_t)k*4 + c)*HW + i];
        den += part[((size_t)k*4 + 3)*HW + i];
    }
    cyc[((size_t)b*3 + c)*HW + i] = s / den;
}

__global__ void flow_kernel(const float* __restrict__ coords, float* __restrict__ out) {
    size_t idx = (size_t)blockIdx.x * 256 + threadIdx.x;
    int x4 = (int)(idx & 255);
    int y4 = (int)((idx >> 8) & 255);
    int ch = (int)((idx >> 16) & 1);
    int b  = (int)(idx >> 17);
    int w = x4 >> 2, h = y4 >> 2;
    int m = h*64 + w;
    float c1 = coords[((size_t)b*2 + ch)*HW + m];
    float c0 = (ch == 0) ? (float)w : (float)h;
    out[OUT_FLOW + idx] = c1 - c0;
}

__global__ void imgout_kernel(const float* __restrict__ attn, const float* __restrict__ cyc,
                              float* __restrict__ out) {
    size_t idx = (size_t)blockIdx.x * 256 + threadIdx.x;
    int x4 = (int)(idx & 255);
    int y4 = (int)((idx >> 8) & 255);
    int rest = (int)(idx >> 16);
    int ch = rest % 3, b = rest / 3;
    int m = (y4 >> 2)*64 + (x4 >> 2);
    out[OUT_IMG  + idx] = attn[((size_t)b*HW + m)*3 + ch];
    out[OUT_CYCO + idx] = cyc[((size_t)b*3 + ch)*HW + m];
}

__global__ void loss_partial_kernel(const float* __restrict__ xf, const float* __restrict__ yf,
                                    const float* __restrict__ means, const float* __restrict__ rnorms,
                                    float* __restrict__ part) {
    __shared__ float red[256];
    size_t base = (size_t)blockIdx.x * 4096;
    float s = 0.f;
    for (int k = 0; k < 16; ++k) {
        size_t id = base + (size_t)k*256 + threadIdx.x;
        int m  = (int)(id & (HW - 1));
        int bc = (int)(id >> 12);
        int b  = bc >> 8;
        float th = (xf[id] - means[bc])          * rnorms[(size_t)b*HW + m];
        float ph = (yf[id] - means[NB*NCH + bc]) * rnorms[(size_t)(NB + b)*HW + m];
        s += fabsf(th - ph);
    }
    red[threadIdx.x] = s; __syncthreads();
    for (int st = 128; st > 0; st >>= 1) {
        if (threadIdx.x < st) red[threadIdx.x] += red[threadIdx.x + st];
        __syncthreads();
    }
    if (threadIdx.x == 0) part[blockIdx.x] = red[0];
}

__global__ void loss_final_kernel(const float* __restrict__ part, float* __restrict__ out) {
    __shared__ float red[256];
    float s = 0.f;
    for (int k = threadIdx.x; k < 1024; k += 256) s += part[k];
    red[threadIdx.x] = s; __syncthreads();
    for (int st = 128; st > 0; st >>= 1) {
        if (threadIdx.x < st) red[threadIdx.x] += red[threadIdx.x + st];
        __syncthreads();
    }
    if (threadIdx.x == 0) out[OUT_LOSS] = red[0] * (1.0f / 4194304.0f);
}

extern "C" void kernel_launch(void* const* d_in, const int* in_sizes, int n_in,
                              void* d_out, int out_size, void* d_ws, size_t ws_size,
                              hipStream_t stream) {
    (void)in_sizes; (void)n_in; (void)out_size; (void)ws_size;
    const float* xf   = (const float*)d_in[0];
    const float* yf   = (const float*)d_in[1];
    const float* yimg = (const float*)d_in[2];
    float* out = (float*)d_out;
    float* ws  = (float*)d_ws;

    _Float16* yf16 = (_Float16*)(ws + OFF_YT);
    float* yi      = ws + OFF_YI;
    float* means   = ws + OFF_MEAN;
    float* rnorms  = ws + OFF_RNORM;
    float* nsqp    = ws + OFF_NSQP;
    float* fbuf    = ws + OFF_F;
    _Float16* yph  = (_Float16*)(ws + OFF_YP);
    float* rowp    = ws + OFF_ROWP;
    float* colp    = ws + OFF_COLP;
    float* rmax    = ws + OFF_RMAX;
    float* rsuminv = ws + OFF_RSUM;
    float* cmax    = ws + OFF_CMAX;
    float* coords  = ws + OFF_COORD;
    float* attn    = ws + OFF_ATTN;
    float* cyc     = ws + OFF_CYC;
    float* cycp    = ws + OFF_CYCP;
    float* lossp   = ws + OFF_LOSSP;
    _Float16* th = (_Float16*)(ws + OFF_F16);
    _Float16* tl = th + (size_t)HW*NCH;
    _Float16* ph = tl + (size_t)HW*NCH;
    _Float16* pl = ph + (size_t)HW*NCH;

    mean_kernel        <<<dim3(NB*NCH, 2),   256, 0, stream>>>(xf, yf, means);
    ycast_kernel       <<<2048,              256, 0, stream>>>(yf, yf16);
    avgpool_kernel     <<<NB*3*HW/256,       256, 0, stream>>>(yimg, yi);

    for (int b = 0; b < NB; ++b) {
        prep_kernel          <<<dim3(8, 128, 2), 256, 0, stream>>>(xf, yf, means, th, tl, ph, pl,
                                                                   nsqp, b);
        nsq_combine_kernel   <<<dim3(16, 2),     256, 0, stream>>>(nsqp, rnorms, b);
        gemm_f_kernel        <<<dim3(32, 32),    512, 0, stream>>>(th, tl, ph, pl, rnorms, yi,
                                                                   fbuf, rowp, colp, b);
        rowcol_combine_kernel<<<dim3(16, 2),     256, 0, stream>>>(rowp, colp, rmax, rsuminv,
                                                                   coords, attn, cmax, b);
        gemm_y_kernel        <<<dim3(64, 4),     512, 0, stream>>>(fbuf, rmax, yf16, yph, b);
        ycombine_kernel      <<<NCH*HW/256,      256, 0, stream>>>(yph, rsuminv, out, b);
        cyc_partial_kernel   <<<dim3(16, 32),    256, 0, stream>>>(fbuf, cmax, attn, cycp, b);
        cyc_combine_kernel   <<<dim3(16, 3),     256, 0, stream>>>(cycp, cyc, b);
    }

    flow_kernel        <<<NB*2*65536/256, 256, 0, stream>>>(coords, out);
    imgout_kernel      <<<NB*3*65536/256, 256, 0, stream>>>(attn, cyc, out);
    loss_partial_kernel<<<1024,           256, 0, stream>>>(xf, yf, means, rnorms, lossp);
    loss_final_kernel  <<<1,              256, 0, stream>>>(lossp, out);
}

// Round 16
// 503.277 us; speedup vs baseline: 1.1777x; 1.0252x over previous
//
#include <hip/hip_runtime.h>
#include <math.h>

#define HW   4096
#define NCH  256
#define NB   4

constexpr float TEMP  = (float)(0.0001 * 5.0);
constexpr float INV_T = 1.0f / TEMP;
constexpr float EPSN  = 2.220446049250313e-16f;

typedef __attribute__((ext_vector_type(8))) _Float16 f16x8;
typedef __attribute__((ext_vector_type(4))) _Float16 f16x4;
typedef __attribute__((ext_vector_type(4))) float    f32x4;

// ---------------- workspace layout (in floats) ----------------
constexpr size_t OFF_YT    = 0;                                 // yf16: NB*HW*NCH f16
constexpr size_t OFF_YI    = OFF_YT    + (size_t)NB*HW*NCH;     // NB*3*HW
constexpr size_t OFF_MEAN  = OFF_YI    + (size_t)NB*3*HW;       // 2*NB*NCH
constexpr size_t OFF_RNORM = OFF_MEAN  + (size_t)2*NB*NCH;      // 2*NB*HW
constexpr size_t OFF_NSQP  = OFF_RNORM + (size_t)2*NB*HW;       // 2*NB*8*HW
constexpr size_t OFF_F     = OFF_NSQP  + (size_t)2*NB*8*HW;     // z: HW*HW f16 (half used)
constexpr size_t OFF_YP    = OFF_F     + (size_t)HW*HW;         // region reused
constexpr size_t OFF_ROWP  = OFF_YP;                            // [32 ntile][7][HW]
constexpr size_t OFF_COLP  = OFF_YP + (size_t)32*7*HW;          // [32 mtile][1][HW] (max only)
constexpr size_t OFF_RMAX  = OFF_YP    + (size_t)8*NCH*HW;
constexpr size_t OFF_RSUM  = OFF_RMAX  + HW;
constexpr size_t OFF_CMAX  = OFF_RSUM  + HW;
constexpr size_t OFF_RMB   = OFF_CMAX  + HW;                // [32 ntile][HW m] block row maxes
constexpr size_t OFF_COORD = OFF_RMB   + (size_t)32*HW;     // NB*2*HW
constexpr size_t OFF_ATTN  = OFF_COORD + (size_t)NB*2*HW;   // NB*HW*3
constexpr size_t OFF_CYC   = OFF_ATTN  + (size_t)NB*HW*3;   // NB*3*HW
constexpr size_t OFF_CYCP  = OFF_CYC   + (size_t)NB*3*HW;   // 32*4*HW
constexpr size_t OFF_LOSSP = OFF_CYCP  + (size_t)32*4*HW;   // 1024
constexpr size_t OFF_F16   = OFF_LOSSP + 1024;              // 4 * 524288 floats

// ---------------- output layout (floats) ----------------
constexpr size_t OUT_Y    = 0;
constexpr size_t OUT_FLOW = (size_t)NB*NCH*HW;
constexpr size_t OUT_IMG  = OUT_FLOW + (size_t)NB*2*256*256;
constexpr size_t OUT_CYCO = OUT_IMG  + (size_t)NB*3*256*256;
constexpr size_t OUT_LOSS = OUT_CYCO + (size_t)NB*3*256*256;

__device__ __forceinline__ void gload16(const void* g, void* l) {
    __builtin_amdgcn_global_load_lds(
        (const __attribute__((address_space(1))) unsigned int*)g,
        (__attribute__((address_space(3))) unsigned int*)l, 16, 0, 0);
}

__global__ void mean_kernel(const float* __restrict__ xf, const float* __restrict__ yf,
                            float* __restrict__ means) {
    const float* src = (blockIdx.y == 0 ? xf : yf) + (size_t)blockIdx.x * HW;
    float s = 0.f;
    for (int i = threadIdx.x; i < HW; i += 256) s += src[i];
    __shared__ float red[256];
    red[threadIdx.x] = s; __syncthreads();
    for (int st = 128; st > 0; st >>= 1) {
        if (threadIdx.x < st) red[threadIdx.x] += red[threadIdx.x + st];
        __syncthreads();
    }
    if (threadIdx.x == 0) means[blockIdx.y * (NB*NCH) + blockIdx.x] = red[0] * (1.0f / HW);
}

__global__ void nsq_combine_kernel(const float* __restrict__ part, float* __restrict__ rnorms,
                                   int b) {
    int t = blockIdx.y;
    int m = blockIdx.x * 256 + threadIdx.x;
    const float* p = part + ((size_t)t*NB + b) * 8 * HW + m;
    float s = 0.f;
    for (int k = 0; k < 8; ++k) s += p[(size_t)k * HW];
    rnorms[((size_t)t*NB + b) * HW + m] = 1.0f / (sqrtf(s) + EPSN);
}

__global__ void ycast_kernel(const float* __restrict__ yf, _Float16* __restrict__ yf16) {
    size_t i = ((size_t)blockIdx.x * 256 + threadIdx.x) * 8;
    const float4* s = (const float4*)(yf + i);
    float4 v0 = s[0], v1 = s[1];
    f16x8 o;
    o[0]=(_Float16)v0.x; o[1]=(_Float16)v0.y; o[2]=(_Float16)v0.z; o[3]=(_Float16)v0.w;
    o[4]=(_Float16)v1.x; o[5]=(_Float16)v1.y; o[6]=(_Float16)v1.z; o[7]=(_Float16)v1.w;
    *(f16x8*)(yf16 + i) = o;
}

__global__ void prep_kernel(const float* __restrict__ xf, const float* __restrict__ yf,
                            const float* __restrict__ means,
                            _Float16* __restrict__ th, _Float16* __restrict__ tl,
                            _Float16* __restrict__ ph, _Float16* __restrict__ pl,
                            float* __restrict__ nsqp, int b) {
    __shared__ float tile[32][33];
    __shared__ float sqr[8][33];
    int t = blockIdx.z;
    int c0 = blockIdx.x * 32, m0 = blockIdx.y * 32;
    const float* src = (t == 0 ? xf : yf) + (size_t)b * NCH * HW;
    const float* mn  = means + t * (NB*NCH) + b * NCH;
    int tx = threadIdx.x & 31, ty = threadIdx.x >> 5;
    float sq = 0.f;
    for (int i = ty; i < 32; i += 8) {
        float v = src[(size_t)(c0 + i) * HW + m0 + tx] - mn[c0 + i];
        tile[i][tx] = v;
        sq += v * v;
    }
    sqr[ty][tx] = sq;
    __syncthreads();
    _Float16* H = (t == 0 ? th : ph);
    _Float16* L = (t == 0 ? tl : pl);
    for (int i = ty; i < 32; i += 8) {
        float v = tile[tx][i];
        _Float16 h = (_Float16)v;
        _Float16 l = (_Float16)(v - (float)h);
        H[(size_t)(m0 + i)*NCH + c0 + tx] = h;
        L[(size_t)(m0 + i)*NCH + c0 + tx] = l;
    }
    if (ty == 0) {
        float s = 0.f;
        #pragma unroll
        for (int k = 0; k < 8; ++k) s += sqr[k][tx];
        nsqp[(((size_t)t*NB + b) * 8 + blockIdx.x) * HW + m0 + tx] = s;
    }
}

__global__ void avgpool_kernel(const float* __restrict__ yimg, float* __restrict__ yi) {
    size_t idx = (size_t)blockIdx.x * 256 + threadIdx.x;
    int m  = (int)(idx & (HW - 1));
    int bc = (int)(idx >> 12);
    int h = m >> 6, w = m & 63;
    const float* p = yimg + (size_t)bc * 65536 + (size_t)(h*4) * 256 + w*4;
    float s = 0.f;
    #pragma unroll
    for (int dy = 0; dy < 4; ++dy) {
        #pragma unroll
        for (int dx = 0; dx < 4; ++dx) s += p[dy*256 + dx];
    }
    yi[idx] = s * (1.0f/16.0f);
}

// f^T accumulator GEMM (R13 structure): 128x128 tile, 8 waves, BK=32, 2-phase dbuf.
// Output: z = (f - bm_row)/T stored as f16 (half the write bytes of fp32 f).
// Also: row max + 6 exp row sums, col MAX, rmb (block row maxes, dedicated buffer).
__global__ __launch_bounds__(512) void gemm_f_kernel(
        const _Float16* __restrict__ th, const _Float16* __restrict__ tl,
        const _Float16* __restrict__ ph, const _Float16* __restrict__ pl,
        const float* __restrict__ rnorms, const float* __restrict__ yi,
        _Float16* __restrict__ zh, float* __restrict__ rowp, float* __restrict__ colp,
        float* __restrict__ rmb, int b) {
    __shared__ char lds[2][4][8192];
    int tid  = threadIdx.x;
    int lane = tid & 63;
    int w = tid >> 6;
    int wm = w >> 2;       // 0..1  n-half (A/phi)
    int wn = w & 3;        // 0..3  m-quarter (B/theta)
    int m0 = blockIdx.y * 128, n0 = blockIdx.x * 128;

    int o0 = tid * 16;
    int r0 = o0 >> 6, s0 = (o0 >> 4) & 3, g0 = s0 ^ ((r0 >> 1) & 3);
    size_t ga0 = (size_t)(n0 + r0)*NCH + g0*8;   // phi row (n)
    size_t gb0 = (size_t)(m0 + r0)*NCH + g0*8;   // theta row (m)

    int fra = wm*64 + (lane & 15);   // A fragment rows (n-local), +i*16, i<4
    int frb = wn*32 + (lane & 15);   // B fragment rows (m-local), +j*16, j<2
    int ks  = lane >> 4;

    auto STAGE = [&](int buf, int k0) {
        gload16(ph + ga0 + k0, &lds[buf][0][o0]);
        gload16(pl + ga0 + k0, &lds[buf][1][o0]);
        gload16(th + gb0 + k0, &lds[buf][2][o0]);
        gload16(tl + gb0 + k0, &lds[buf][3][o0]);
    };

    f32x4 acc[4][2];
    #pragma unroll
    for (int i = 0; i < 4; ++i)
        #pragma unroll
        for (int j = 0; j < 2; ++j) acc[i][j] = (f32x4){0.f, 0.f, 0.f, 0.f};

    STAGE(0, 0);
    __syncthreads();
    int cur = 0;
    for (int kt = 0; kt < 8; ++kt) {
        if (kt < 7) STAGE(cur ^ 1, (kt + 1) * 32);

        f16x8 ah[4], al[4], bh[2], bl[2];
        #pragma unroll
        for (int i = 0; i < 4; ++i) {
            int rowa = fra + i*16;
            int offa = rowa*64 + ((ks ^ ((rowa >> 1) & 3)) << 4);
            ah[i] = *(const f16x8*)&lds[cur][0][offa];
            al[i] = *(const f16x8*)&lds[cur][1][offa];
        }
        #pragma unroll
        for (int j = 0; j < 2; ++j) {
            int rowb = frb + j*16;
            int offb = rowb*64 + ((ks ^ ((rowb >> 1) & 3)) << 4);
            bh[j] = *(const f16x8*)&lds[cur][2][offb];
            bl[j] = *(const f16x8*)&lds[cur][3][offb];
        }
        __builtin_amdgcn_s_setprio(1);
        #pragma unroll
        for (int i = 0; i < 4; ++i)
            #pragma unroll
            for (int j = 0; j < 2; ++j) {
                acc[i][j] = __builtin_amdgcn_mfma_f32_16x16x32_f16(ah[i], bh[j], acc[i][j], 0, 0, 0);
                acc[i][j] = __builtin_amdgcn_mfma_f32_16x16x32_f16(ah[i], bl[j], acc[i][j], 0, 0, 0);
                acc[i][j] = __builtin_amdgcn_mfma_f32_16x16x32_f16(al[i], bh[j], acc[i][j], 0, 0, 0);
            }
        __builtin_amdgcn_s_setprio(0);
        __syncthreads();
        cur ^= 1;
    }

    // ---- scale in place: f[m][n] = accT * rnx[m] * rny[n] ----
    const float* rnx = rnorms + (size_t)b * HW;
    const float* rny = rnorms + (size_t)(NB + b) * HW;
    int mg[2];  float rxv[2];
    #pragma unroll
    for (int j = 0; j < 2; ++j) {
        mg[j] = m0 + wn*32 + j*16 + (lane & 15);
        rxv[j] = rnx[mg[j]];
    }
    int nl0 = wm*64 + (lane >> 4)*4;
    #pragma unroll
    for (int i = 0; i < 4; ++i)
        #pragma unroll
        for (int r = 0; r < 4; ++r) {
            float ry = rny[n0 + nl0 + i*16 + r];
            #pragma unroll
            for (int j = 0; j < 2; ++j) acc[i][j][r] *= rxv[j] * ry;
        }

    // ---- stats ----
    float* S     = (float*)&lds[0][0][0];
    float* rowm  = S;          // [2 wm][128 m]
    float* sums6 = S + 256;    // [2 wm][128 m][6]
    float* colm  = S + 1792;   // [4 wn][128 n]

    // phase A: per-wave maxes
    #pragma unroll
    for (int j = 0; j < 2; ++j) {
        float v = acc[0][j][0];
        #pragma unroll
        for (int i = 0; i < 4; ++i)
            #pragma unroll
            for (int r = 0; r < 4; ++r) v = fmaxf(v, acc[i][j][r]);
        v = fmaxf(v, __shfl_xor(v, 16));
        v = fmaxf(v, __shfl_xor(v, 32));
        if (lane < 16) rowm[wm*128 + wn*32 + j*16 + lane] = v;
    }
    #pragma unroll
    for (int i = 0; i < 4; ++i)
        #pragma unroll
        for (int r = 0; r < 4; ++r) {
            float v = fmaxf(acc[i][0][r], acc[i][1][r]);
            #pragma unroll
            for (int d = 1; d < 16; d <<= 1) v = fmaxf(v, __shfl_xor(v, d));
            if ((lane & 15) == 0) colm[wn*128 + nl0 + i*16 + r] = v;
        }
    __syncthreads();

    // phase B: row exp sums vs block maxes + z (f16) stores
    float bm[2];
    #pragma unroll
    for (int j = 0; j < 2; ++j) {
        int ml = wn*32 + j*16 + (lane & 15);
        bm[j] = fmaxf(rowm[ml], rowm[128 + ml]);
    }
    float a6[2][6];
    #pragma unroll
    for (int j = 0; j < 2; ++j)
        #pragma unroll
        for (int q = 0; q < 6; ++q) a6[j][q] = 0.f;
    const float* yib = yi + (size_t)b * 3 * HW;
    #pragma unroll
    for (int i = 0; i < 4; ++i) {
        f16x4 zq[2];
        #pragma unroll
        for (int r = 0; r < 4; ++r) {
            int ng = n0 + nl0 + i*16 + r;
            float xc = (float)(ng & 63), yc = (float)(ng >> 6);
            float y0 = yib[ng], y1 = yib[HW + ng], y2 = yib[2*HW + ng];
            #pragma unroll
            for (int j = 0; j < 2; ++j) {
                float z = (acc[i][j][r] - bm[j]) * INV_T;
                float e = __expf(z);
                zq[j][r] = (_Float16)z;
                a6[j][0] += e;      a6[j][1] += e*xc; a6[j][2] += e*yc;
                a6[j][3] += e*y0;   a6[j][4] += e*y1; a6[j][5] += e*y2;
            }
        }
        #pragma unroll
        for (int j = 0; j < 2; ++j)
            *(f16x4*)&zh[(size_t)mg[j]*HW + n0 + nl0 + i*16] = zq[j];
    }
    #pragma unroll
    for (int j = 0; j < 2; ++j)
        #pragma unroll
        for (int q = 0; q < 6; ++q) {
            float v = a6[j][q];
            v += __shfl_xor(v, 16);
            v += __shfl_xor(v, 32);
            if (lane < 16) sums6[(wm*128 + wn*32 + j*16 + lane)*6 + q] = v;
        }
    __syncthreads();

    // phase C: global partial writes
    if (tid < 128) {
        int ml = tid;
        float m2 = fmaxf(rowm[ml], rowm[128 + ml]);
        rowp[((size_t)blockIdx.x*7 + 0)*HW + m0 + ml] = m2;
        rmb[(size_t)blockIdx.x*HW + m0 + ml] = m2;
        #pragma unroll
        for (int q = 0; q < 6; ++q)
            rowp[((size_t)blockIdx.x*7 + 1 + q)*HW + m0 + ml] =
                sums6[ml*6 + q] + sums6[(128 + ml)*6 + q];
    } else if (tid < 256) {
        int nl = tid - 128;
        float c2 = fmaxf(fmaxf(colm[nl], colm[128 + nl]),
                         fmaxf(colm[256 + nl], colm[384 + nl]));
        colp[(size_t)blockIdx.y*HW + n0 + nl] = c2;
    }
}

// merged combine: y==0 -> row stats; y==1 -> col max only
__global__ void rowcol_combine_kernel(const float* __restrict__ rowp,
        const float* __restrict__ colp,
        float* __restrict__ rmax, float* __restrict__ rsuminv,
        float* __restrict__ coords, float* __restrict__ attn,
        float* __restrict__ cmax, int b) {
    int idx = blockIdx.x * 256 + threadIdx.x;
    if (blockIdx.y == 0) {
        int m = idx;
        float gm = -3.0e38f;
        for (int t = 0; t < 32; ++t) gm = fmaxf(gm, rowp[((size_t)t*7)*HW + m]);
        float S=0, CX=0, CY=0, A0=0, A1=0, A2=0;
        for (int t = 0; t < 32; ++t) {
            const float* p = rowp + (size_t)t*7*HW + m;
            float wgt = __expf((p[0] - gm) * INV_T);
            S  += p[1*HW] * wgt; CX += p[2*HW] * wgt; CY += p[3*HW] * wgt;
            A0 += p[4*HW] * wgt; A1 += p[5*HW] * wgt; A2 += p[6*HW] * wgt;
        }
        float inv = 1.0f / S;
        rmax[m] = gm; rsuminv[m] = inv;
        coords[((size_t)b*2 + 0)*HW + m] = CX * inv;
        coords[((size_t)b*2 + 1)*HW + m] = CY * inv;
        attn[((size_t)b*HW + m)*3 + 0] = A0 * inv;
        attn[((size_t)b*HW + m)*3 + 1] = A1 * inv;
        attn[((size_t)b*HW + m)*3 + 2] = A2 * inv;
    } else {
        int n = idx;
        float gm = -3.0e38f;
        for (int t = 0; t < 32; ++t) gm = fmaxf(gm, colp[(size_t)t*HW + n]);
        cmax[n] = gm;
    }
}

// y partials: A = exp(z)*corr (per 128-K row-block correction), B = yf16.
// split-K=4, tile 64m x 256c, 8 waves; f16 partial output.
__global__ __launch_bounds__(512) void gemm_y_kernel(const _Float16* __restrict__ zh,
        const float* __restrict__ rmax, const float* __restrict__ rmb,
        const _Float16* __restrict__ yf16, _Float16* __restrict__ yph, int b) {
    __shared__ __align__(16) char ldsA[4096];
    __shared__ __align__(16) char ldsB[16384];
    int tid  = threadIdx.x;
    int lane = tid & 63;
    int w = tid >> 6, wm = w >> 2, wn = w & 3;
    int m0 = blockIdx.x * 64;
    int ks = blockIdx.y;
    const _Float16* Yb = yf16 + (size_t)b * NCH * HW;

    int ar = tid >> 3, kc = tid & 7;
    int aslot = kc >> 1, ahalf = kc & 1;
    int aoff = ar*64 + ((aslot ^ ((ar >> 1) & 3)) << 4) + ahalf*8;
    float gm = rmax[m0 + ar];
    const _Float16* zrow = zh + (size_t)(m0 + ar)*HW + kc*4;
    const float* rmbm = rmb + (m0 + ar);

    int o0 = tid*16, o1 = o0 + 8192;
    int br0 = o0 >> 6, bs0 = (o0 >> 4) & 3, bg0 = bs0 ^ ((br0 >> 1) & 3);
    int br1 = o1 >> 6, bs1 = (o1 >> 4) & 3, bg1 = bs1 ^ ((br1 >> 1) & 3);
    size_t gb0 = (size_t)br0*HW + bg0*8;
    size_t gb1 = (size_t)br1*HW + bg1*8;

    int fra = wm*32 + (lane & 15);
    int frb = wn*64 + (lane & 15);
    int kslot = lane >> 4;

    f32x4 acc[2][4];
    #pragma unroll
    for (int i = 0; i < 2; ++i)
        #pragma unroll
        for (int j = 0; j < 4; ++j) acc[i][j] = (f32x4){0.f, 0.f, 0.f, 0.f};

    float corrf = 0.f;
    for (int k0 = ks*1024; k0 < ks*1024 + 1024; k0 += 32) {
        gload16(Yb + gb0 + k0, &ldsB[o0]);
        gload16(Yb + gb1 + k0, &ldsB[o1]);
        {
            if ((k0 & 127) == 0)
                corrf = __expf((rmbm[(size_t)(k0 >> 7)*HW] - gm) * INV_T);
            f16x4 zv = *(const f16x4*)(zrow + k0);
            f16x4 pk;
            pk[0] = (_Float16)(__expf((float)zv[0]) * corrf);
            pk[1] = (_Float16)(__expf((float)zv[1]) * corrf);
            pk[2] = (_Float16)(__expf((float)zv[2]) * corrf);
            pk[3] = (_Float16)(__expf((float)zv[3]) * corrf);
            *(f16x4*)&ldsA[aoff] = pk;
        }
        __syncthreads();

        f16x8 af[2], bf[4];
        #pragma unroll
        for (int i = 0; i < 2; ++i) {
            int rowa = fra + i*16;
            af[i] = *(const f16x8*)&ldsA[rowa*64 + ((kslot ^ ((rowa >> 1) & 3)) << 4)];
        }
        #pragma unroll
        for (int j = 0; j < 4; ++j) {
            int rowb = frb + j*16;
            bf[j] = *(const f16x8*)&ldsB[rowb*64 + ((kslot ^ ((rowb >> 1) & 3)) << 4)];
        }
        __builtin_amdgcn_s_setprio(1);
        #pragma unroll
        for (int i = 0; i < 2; ++i)
            #pragma unroll
            for (int j = 0; j < 4; ++j)
                acc[i][j] = __builtin_amdgcn_mfma_f32_16x16x32_f16(af[i], bf[j], acc[i][j], 0, 0, 0);
        __builtin_amdgcn_s_setprio(0);
        __syncthreads();
    }

    #pragma unroll
    for (int i = 0; i < 2; ++i) {
        int m = m0 + wm*32 + i*16 + (lane >> 4) * 4;
        #pragma unroll
        for (int j = 0; j < 4; ++j) {
            int c = wn*64 + j*16 + (lane & 15);
            f16x4 v;
            #pragma unroll
            for (int r = 0; r < 4; ++r) v[r] = (_Float16)acc[i][j][r];
            *(f16x4*)(yph + ((size_t)ks*NCH + c)*HW + m) = v;
        }
    }
}

__global__ void ycombine_kernel(const _Float16* __restrict__ yph, const float* __restrict__ rsuminv,
                                float* __restrict__ out, int b) {
    size_t idx = (size_t)blockIdx.x * 256 + threadIdx.x;
    int m = (int)(idx & (HW - 1));
    float s = 0.f;
    #pragma unroll
    for (int k = 0; k < 4; ++k) s += (float)yph[(size_t)k*NCH*HW + idx];
    out[OUT_Y + (size_t)b*NCH*HW + idx] = s * rsuminv[m];
}

// cyc partial over row-chunks of 128; reads z f16, corrects by (rmb - cmax)/T
__global__ __launch_bounds__(256) void cyc_partial_kernel(const _Float16* __restrict__ zh,
        const float* __restrict__ cmax, const float* __restrict__ rmb,
        const float* __restrict__ attn, float* __restrict__ part, int b) {
    __shared__ float at[128*3];
    __shared__ float bmL[2][128];
    int i  = blockIdx.x * 256 + threadIdx.x;
    int j0 = blockIdx.y * 128;
    for (int k = threadIdx.x; k < 384; k += 256)
        at[k] = attn[((size_t)b*HW + j0)*3 + k];
    {
        int k = threadIdx.x;   // 256 threads -> 2 tiles x 128 rows
        bmL[k >> 7][k & 127] = rmb[((size_t)(blockIdx.x*2 + (k >> 7)))*HW + j0 + (k & 127)];
    }
    __syncthreads();
    float cm = cmax[i];
    int tl = threadIdx.x >> 7;
    float a0=0, a1=0, a2=0, a3=0;
    for (int jj = 0; jj < 128; ++jj) {
        float z = (float)zh[(size_t)(j0+jj)*HW + i];
        float e = __expf(z + (bmL[tl][jj] - cm) * INV_T);
        a0 = fmaf(e, at[jj*3+0], a0);
        a1 = fmaf(e, at[jj*3+1], a1);
        a2 = fmaf(e, at[jj*3+2], a2);
        a3 += e;
    }
    part[((size_t)blockIdx.y*4 + 0)*HW + i] = a0;
    part[((size_t)blockIdx.y*4 + 1)*HW + i] = a1;
    part[((size_t)blockIdx.y*4 + 2)*HW + i] = a2;
    part[((size_t)blockIdx.y*4 + 3)*HW + i] = a3;
}

__global__ void cyc_combine_kernel(const float* __restrict__ part,
                                   float* __restrict__ cyc, int b) {
    int i = blockIdx.x * 256 + threadIdx.x;
    int c = blockIdx.y;
    float s = 0.f, den = 0.f;
    for (int k = 0; k < 32; ++k) {
        s   += part[((size_t)k*4 + c)*HW + i];
        den += part[((size_t)k*4 + 3)*HW + i];
    }
    cyc[((size_t)b*3 + c)*HW + i] = s / den;
}

__global__ void flow_kernel(const float* __restrict__ coords, float* __restrict__ out) {
    size_t idx = (size_t)blockIdx.x * 256 + threadIdx.x;
    int x4 = (int)(idx & 255);
    int y4 = (int)((idx >> 8) & 255);
    int ch = (int)((idx >> 16) & 1);
    int b  = (int)(idx >> 17);
    int w = x4 >> 2, h = y4 >> 2;
    int m = h*64 + w;
    float c1 = coords[((size_t)b*2 + ch)*HW + m];
    float c0 = (ch == 0) ? (float)w : (float)h;
    out[OUT_FLOW + idx] = c1 - c0;
}

__global__ void imgout_kernel(const float* __restrict__ attn, const float* __restrict__ cyc,
                              float* __restrict__ out) {
    size_t idx = (size_t)blockIdx.x * 256 + threadIdx.x;
    int x4 = (int)(idx & 255);
    int y4 = (int)((idx >> 8) & 255);
    int rest = (int)(idx >> 16);
    int ch = rest % 3, b = rest / 3;
    int m = (y4 >> 2)*64 + (x4 >> 2);
    out[OUT_IMG  + idx] = attn[((size_t)b*HW + m)*3 + ch];
    out[OUT_CYCO + idx] = cyc[((size_t)b*3 + ch)*HW + m];
}

__global__ void loss_partial_kernel(const float* __restrict__ xf, const float* __restrict__ yf,
                                    const float* __restrict__ means, const float* __restrict__ rnorms,
                                    float* __restrict__ part) {
    __shared__ float red[256];
    size_t base = (size_t)blockIdx.x * 4096;
    float s = 0.f;
    for (int k = 0; k < 16; ++k) {
        size_t id = base + (size_t)k*256 + threadIdx.x;
        int m  = (int)(id & (HW - 1));
        int bc = (int)(id >> 12);
        int b  = bc >> 8;
        float th = (xf[id] - means[bc])          * rnorms[(size_t)b*HW + m];
        float ph = (yf[id] - means[NB*NCH + bc]) * rnorms[(size_t)(NB + b)*HW + m];
        s += fabsf(th - ph);
    }
    red[threadIdx.x] = s; __syncthreads();
    for (int st = 128; st > 0; st >>= 1) {
        if (threadIdx.x < st) red[threadIdx.x] += red[threadIdx.x + st];
        __syncthreads();
    }
    if (threadIdx.x == 0) part[blockIdx.x] = red[0];
}

__global__ void loss_final_kernel(const float* __restrict__ part, float* __restrict__ out) {
    __shared__ float red[256];
    float s = 0.f;
    for (int k = threadIdx.x; k < 1024; k += 256) s += part[k];
    red[threadIdx.x] = s; __syncthreads();
    for (int st = 128; st > 0; st >>= 1) {
        if (threadIdx.x < st) red[threadIdx.x] += red[threadIdx.x + st];
        __syncthreads();
    }
    if (threadIdx.x == 0) out[OUT_LOSS] = red[0] * (1.0f / 4194304.0f);
}

extern "C" void kernel_launch(void* const* d_in, const int* in_sizes, int n_in,
                              void* d_out, int out_size, void* d_ws, size_t ws_size,
                              hipStream_t stream) {
    (void)in_sizes; (void)n_in; (void)out_size; (void)ws_size;
    const float* xf   = (const float*)d_in[0];
    const float* yf   = (const float*)d_in[1];
    const float* yimg = (const float*)d_in[2];
    float* out = (float*)d_out;
    float* ws  = (float*)d_ws;

    _Float16* yf16 = (_Float16*)(ws + OFF_YT);
    float* yi      = ws + OFF_YI;
    float* means   = ws + OFF_MEAN;
    float* rnorms  = ws + OFF_RNORM;
    float* nsqp    = ws + OFF_NSQP;
    _Float16* zh   = (_Float16*)(ws + OFF_F);
    _Float16* yph  = (_Float16*)(ws + OFF_YP);
    float* rowp    = ws + OFF_ROWP;
    float* colp    = ws + OFF_COLP;
    float* rmax    = ws + OFF_RMAX;
    float* rsuminv = ws + OFF_RSUM;
    float* cmax    = ws + OFF_CMAX;
    float* rmb     = ws + OFF_RMB;
    float* coords  = ws + OFF_COORD;
    float* attn    = ws + OFF_ATTN;
    float* cyc     = ws + OFF_CYC;
    float* cycp    = ws + OFF_CYCP;
    float* lossp   = ws + OFF_LOSSP;
    _Float16* th = (_Float16*)(ws + OFF_F16);
    _Float16* tl = th + (size_t)HW*NCH;
    _Float16* ph = tl + (size_t)HW*NCH;
    _Float16* pl = ph + (size_t)HW*NCH;

    mean_kernel        <<<dim3(NB*NCH, 2),   256, 0, stream>>>(xf, yf, means);
    ycast_kernel       <<<2048,              256, 0, stream>>>(yf, yf16);
    avgpool_kernel     <<<NB*3*HW/256,       256, 0, stream>>>(yimg, yi);

    for (int b = 0; b < NB; ++b) {
        prep_kernel          <<<dim3(8, 128, 2), 256, 0, stream>>>(xf, yf, means, th, tl, ph, pl,
                                                                   nsqp, b);
        nsq_combine_kernel   <<<dim3(16, 2),     256, 0, stream>>>(nsqp, rnorms, b);
        gemm_f_kernel        <<<dim3(32, 32),    512, 0, stream>>>(th, tl, ph, pl, rnorms, yi,
                                                                   zh, rowp, colp, rmb, b);
        rowcol_combine_kernel<<<dim3(16, 2),     256, 0, stream>>>(rowp, colp, rmax, rsuminv,
                                                                   coords, attn, cmax, b);
        gemm_y_kernel        <<<dim3(64, 4),     512, 0, stream>>>(zh, rmax, rmb, yf16, yph, b);
        ycombine_kernel      <<<NCH*HW/256,      256, 0, stream>>>(yph, rsuminv, out, b);
        cyc_partial_kernel   <<<dim3(16, 32),    256, 0, stream>>>(zh, cmax, rmb, attn, cycp, b);
        cyc_combine_kernel   <<<dim3(16, 3),     256, 0, stream>>>(cycp, cyc, b);
    }

    flow_kernel        <<<NB*2*65536/256, 256, 0, stream>>>(coords, out);
    imgout_kernel      <<<NB*3*65536/256, 256, 0, stream>>>(attn, cyc, out);
    loss_partial_kernel<<<1024,           256, 0, stream>>>(xf, yf, means, rnorms, lossp);
    loss_final_kernel  <<<1,              256, 0, stream>>>(lossp, out);
}

// Round 18
// 477.682 us; speedup vs baseline: 1.2408x; 1.0536x over previous
//
#include <hip/hip_runtime.h>
#include <math.h>

#define HW   4096
#define NCH  256
#define NB   4

constexpr float TEMP  = (float)(0.0001 * 5.0);
constexpr float INV_T = 1.0f / TEMP;
constexpr float EPSN  = 2.220446049250313e-16f;

typedef __attribute__((ext_vector_type(8))) _Float16 f16x8;
typedef __attribute__((ext_vector_type(4))) _Float16 f16x4;
typedef __attribute__((ext_vector_type(4))) float    f32x4;

// ---------------- workspace layout (in floats) ----------------
constexpr size_t OFF_YT    = 0;                                 // yf16: NB*HW*NCH f16
constexpr size_t OFF_YI    = OFF_YT    + (size_t)NB*HW*NCH;     // NB*3*HW
constexpr size_t OFF_MEAN  = OFF_YI    + (size_t)NB*3*HW;       // 2*NB*NCH
constexpr size_t OFF_RNORM = OFF_MEAN  + (size_t)2*NB*NCH;      // 2*NB*HW
constexpr size_t OFF_NSQP  = OFF_RNORM + (size_t)2*NB*HW;       // 2*NB*8*HW
constexpr size_t OFF_F     = OFF_NSQP  + (size_t)2*NB*8*HW;     // z: HW*HW f16 in LOWER half
// upper half of F region (floats) — z only uses the lower 32 MB
constexpr size_t OFF_ZUP   = OFF_F     + (size_t)HW*HW/2;
constexpr size_t OFF_CYCP  = OFF_ZUP;                           // NB*32*4*HW
constexpr size_t OFF_ROWP  = OFF_CYCP  + (size_t)NB*32*4*HW;    // 32*7*HW
constexpr size_t OFF_COLP  = OFF_ROWP  + (size_t)32*7*HW;       // 32*HW
constexpr size_t OFF_YP    = OFF_F     + (size_t)HW*HW;         // yph: NB*4*NCH*HW f16
constexpr size_t OFF_RMAX  = OFF_YP    + (size_t)8*NCH*HW;
constexpr size_t OFF_RSUM  = OFF_RMAX  + HW;                // NB*HW
constexpr size_t OFF_CMAX  = OFF_RSUM  + (size_t)NB*HW;
constexpr size_t OFF_RMB   = OFF_CMAX  + HW;                // [32 ntile][HW m]
constexpr size_t OFF_COORD = OFF_RMB   + (size_t)32*HW;     // NB*2*HW
constexpr size_t OFF_ATTN  = OFF_COORD + (size_t)NB*2*HW;   // NB*HW*3
constexpr size_t OFF_CYC   = OFF_ATTN  + (size_t)NB*HW*3;   // NB*3*HW
constexpr size_t OFF_LOSSP = OFF_CYC   + (size_t)NB*3*HW;   // 1024
constexpr size_t OFF_F16   = OFF_LOSSP + 1024;              // 4 * 524288 floats

// ---------------- output layout (floats) ----------------
constexpr size_t OUT_Y    = 0;
constexpr size_t OUT_FLOW = (size_t)NB*NCH*HW;
constexpr size_t OUT_IMG  = OUT_FLOW + (size_t)NB*2*256*256;
constexpr size_t OUT_CYCO = OUT_IMG  + (size_t)NB*3*256*256;
constexpr size_t OUT_LOSS = OUT_CYCO + (size_t)NB*3*256*256;

__device__ __forceinline__ void gload16(const void* g, void* l) {
    __builtin_amdgcn_global_load_lds(
        (const __attribute__((address_space(1))) unsigned int*)g,
        (__attribute__((address_space(3))) unsigned int*)l, 16, 0, 0);
}

__global__ void mean_kernel(const float* __restrict__ xf, const float* __restrict__ yf,
                            float* __restrict__ means) {
    const float* src = (blockIdx.y == 0 ? xf : yf) + (size_t)blockIdx.x * HW;
    float s = 0.f;
    for (int i = threadIdx.x; i < HW; i += 256) s += src[i];
    __shared__ float red[256];
    red[threadIdx.x] = s; __syncthreads();
    for (int st = 128; st > 0; st >>= 1) {
        if (threadIdx.x < st) red[threadIdx.x] += red[threadIdx.x + st];
        __syncthreads();
    }
    if (threadIdx.x == 0) means[blockIdx.y * (NB*NCH) + blockIdx.x] = red[0] * (1.0f / HW);
}

__global__ void nsq_combine_kernel(const float* __restrict__ part, float* __restrict__ rnorms,
                                   int b) {
    int t = blockIdx.y;
    int m = blockIdx.x * 256 + threadIdx.x;
    const float* p = part + ((size_t)t*NB + b) * 8 * HW + m;
    float s = 0.f;
    for (int k = 0; k < 8; ++k) s += p[(size_t)k * HW];
    rnorms[((size_t)t*NB + b) * HW + m] = 1.0f / (sqrtf(s) + EPSN);
}

__global__ void ycast_kernel(const float* __restrict__ yf, _Float16* __restrict__ yf16) {
    size_t i = ((size_t)blockIdx.x * 256 + threadIdx.x) * 8;
    const float4* s = (const float4*)(yf + i);
    float4 v0 = s[0], v1 = s[1];
    f16x8 o;
    o[0]=(_Float16)v0.x; o[1]=(_Float16)v0.y; o[2]=(_Float16)v0.z; o[3]=(_Float16)v0.w;
    o[4]=(_Float16)v1.x; o[5]=(_Float16)v1.y; o[6]=(_Float16)v1.z; o[7]=(_Float16)v1.w;
    *(f16x8*)(yf16 + i) = o;
}

__global__ void prep_kernel(const float* __restrict__ xf, const float* __restrict__ yf,
                            const float* __restrict__ means,
                            _Float16* __restrict__ th, _Float16* __restrict__ tl,
                            _Float16* __restrict__ ph, _Float16* __restrict__ pl,
                            float* __restrict__ nsqp, int b) {
    __shared__ float tile[32][33];
    __shared__ float sqr[8][33];
    int t = blockIdx.z;
    int c0 = blockIdx.x * 32, m0 = blockIdx.y * 32;
    const float* src = (t == 0 ? xf : yf) + (size_t)b * NCH * HW;
    const float* mn  = means + t * (NB*NCH) + b * NCH;
    int tx = threadIdx.x & 31, ty = threadIdx.x >> 5;
    float sq = 0.f;
    for (int i = ty; i < 32; i += 8) {
        float v = src[(size_t)(c0 + i) * HW + m0 + tx] - mn[c0 + i];
        tile[i][tx] = v;
        sq += v * v;
    }
    sqr[ty][tx] = sq;
    __syncthreads();
    _Float16* H = (t == 0 ? th : ph);
    _Float16* L = (t == 0 ? tl : pl);
    for (int i = ty; i < 32; i += 8) {
        float v = tile[tx][i];
        _Float16 h = (_Float16)v;
        _Float16 l = (_Float16)(v - (float)h);
        H[(size_t)(m0 + i)*NCH + c0 + tx] = h;
        L[(size_t)(m0 + i)*NCH + c0 + tx] = l;
    }
    if (ty == 0) {
        float s = 0.f;
        #pragma unroll
        for (int k = 0; k < 8; ++k) s += sqr[k][tx];
        nsqp[(((size_t)t*NB + b) * 8 + blockIdx.x) * HW + m0 + tx] = s;
    }
}

__global__ void avgpool_kernel(const float* __restrict__ yimg, float* __restrict__ yi) {
    size_t idx = (size_t)blockIdx.x * 256 + threadIdx.x;
    int m  = (int)(idx & (HW - 1));
    int bc = (int)(idx >> 12);
    int h = m >> 6, w = m & 63;
    const float* p = yimg + (size_t)bc * 65536 + (size_t)(h*4) * 256 + w*4;
    float s = 0.f;
    #pragma unroll
    for (int dy = 0; dy < 4; ++dy) {
        #pragma unroll
        for (int dx = 0; dx < 4; ++dx) s += p[dy*256 + dx];
    }
    yi[idx] = s * (1.0f/16.0f);
}

// f^T accumulator GEMM (R16-proven): 128x128 tile, 8 waves, BK=32, 2-phase dbuf.
// Output: z = (f - bm_row)/T stored as f16; row stats + col max + rmb.
__global__ __launch_bounds__(512) void gemm_f_kernel(
        const _Float16* __restrict__ th, const _Float16* __restrict__ tl,
        const _Float16* __restrict__ ph, const _Float16* __restrict__ pl,
        const float* __restrict__ rnorms, const float* __restrict__ yi,
        _Float16* __restrict__ zh, float* __restrict__ rowp, float* __restrict__ colp,
        float* __restrict__ rmb, int b) {
    __shared__ char lds[2][4][8192];
    int tid  = threadIdx.x;
    int lane = tid & 63;
    int w = tid >> 6;
    int wm = w >> 2;       // 0..1  n-half (A/phi)
    int wn = w & 3;        // 0..3  m-quarter (B/theta)
    int m0 = blockIdx.y * 128, n0 = blockIdx.x * 128;

    int o0 = tid * 16;
    int r0 = o0 >> 6, s0 = (o0 >> 4) & 3, g0 = s0 ^ ((r0 >> 1) & 3);
    size_t ga0 = (size_t)(n0 + r0)*NCH + g0*8;   // phi row (n)
    size_t gb0 = (size_t)(m0 + r0)*NCH + g0*8;   // theta row (m)

    int fra = wm*64 + (lane & 15);
    int frb = wn*32 + (lane & 15);
    int ks  = lane >> 4;

    auto STAGE = [&](int buf, int k0) {
        gload16(ph + ga0 + k0, &lds[buf][0][o0]);
        gload16(pl + ga0 + k0, &lds[buf][1][o0]);
        gload16(th + gb0 + k0, &lds[buf][2][o0]);
        gload16(tl + gb0 + k0, &lds[buf][3][o0]);
    };

    f32x4 acc[4][2];
    #pragma unroll
    for (int i = 0; i < 4; ++i)
        #pragma unroll
        for (int j = 0; j < 2; ++j) acc[i][j] = (f32x4){0.f, 0.f, 0.f, 0.f};

    STAGE(0, 0);
    __syncthreads();
    int cur = 0;
    for (int kt = 0; kt < 8; ++kt) {
        if (kt < 7) STAGE(cur ^ 1, (kt + 1) * 32);

        f16x8 ah[4], al[4], bh[2], bl[2];
        #pragma unroll
        for (int i = 0; i < 4; ++i) {
            int rowa = fra + i*16;
            int offa = rowa*64 + ((ks ^ ((rowa >> 1) & 3)) << 4);
            ah[i] = *(const f16x8*)&lds[cur][0][offa];
            al[i] = *(const f16x8*)&lds[cur][1][offa];
        }
        #pragma unroll
        for (int j = 0; j < 2; ++j) {
            int rowb = frb + j*16;
            int offb = rowb*64 + ((ks ^ ((rowb >> 1) & 3)) << 4);
            bh[j] = *(const f16x8*)&lds[cur][2][offb];
            bl[j] = *(const f16x8*)&lds[cur][3][offb];
        }
        __builtin_amdgcn_s_setprio(1);
        #pragma unroll
        for (int i = 0; i < 4; ++i)
            #pragma unroll
            for (int j = 0; j < 2; ++j) {
                acc[i][j] = __builtin_amdgcn_mfma_f32_16x16x32_f16(ah[i], bh[j], acc[i][j], 0, 0, 0);
                acc[i][j] = __builtin_amdgcn_mfma_f32_16x16x32_f16(ah[i], bl[j], acc[i][j], 0, 0, 0);
                acc[i][j] = __builtin_amdgcn_mfma_f32_16x16x32_f16(al[i], bh[j], acc[i][j], 0, 0, 0);
            }
        __builtin_amdgcn_s_setprio(0);
        __syncthreads();
        cur ^= 1;
    }

    // ---- scale in place: f[m][n] = accT * rnx[m] * rny[n] ----
    const float* rnx = rnorms + (size_t)b * HW;
    const float* rny = rnorms + (size_t)(NB + b) * HW;
    int mg[2];  float rxv[2];
    #pragma unroll
    for (int j = 0; j < 2; ++j) {
        mg[j] = m0 + wn*32 + j*16 + (lane & 15);
        rxv[j] = rnx[mg[j]];
    }
    int nl0 = wm*64 + (lane >> 4)*4;
    #pragma unroll
    for (int i = 0; i < 4; ++i)
        #pragma unroll
        for (int r = 0; r < 4; ++r) {
            float ry = rny[n0 + nl0 + i*16 + r];
            #pragma unroll
            for (int j = 0; j < 2; ++j) acc[i][j][r] *= rxv[j] * ry;
        }

    // ---- stats ----
    float* S     = (float*)&lds[0][0][0];
    float* rowm  = S;          // [2 wm][128 m]
    float* sums6 = S + 256;    // [2 wm][128 m][6]
    float* colm  = S + 1792;   // [4 wn][128 n]

    #pragma unroll
    for (int j = 0; j < 2; ++j) {
        float v = acc[0][j][0];
        #pragma unroll
        for (int i = 0; i < 4; ++i)
            #pragma unroll
            for (int r = 0; r < 4; ++r) v = fmaxf(v, acc[i][j][r]);
        v = fmaxf(v, __shfl_xor(v, 16));
        v = fmaxf(v, __shfl_xor(v, 32));
        if (lane < 16) rowm[wm*128 + wn*32 + j*16 + lane] = v;
    }
    #pragma unroll
    for (int i = 0; i < 4; ++i)
        #pragma unroll
        for (int r = 0; r < 4; ++r) {
            float v = fmaxf(acc[i][0][r], acc[i][1][r]);
            #pragma unroll
            for (int d = 1; d < 16; d <<= 1) v = fmaxf(v, __shfl_xor(v, d));
            if ((lane & 15) == 0) colm[wn*128 + nl0 + i*16 + r] = v;
        }
    __syncthreads();

    float bm[2];
    #pragma unroll
    for (int j = 0; j < 2; ++j) {
        int ml = wn*32 + j*16 + (lane & 15);
        bm[j] = fmaxf(rowm[ml], rowm[128 + ml]);
    }
    float a6[2][6];
    #pragma unroll
    for (int j = 0; j < 2; ++j)
        #pragma unroll
        for (int q = 0; q < 6; ++q) a6[j][q] = 0.f;
    const float* yib = yi + (size_t)b * 3 * HW;
    #pragma unroll
    for (int i = 0; i < 4; ++i) {
        f16x4 zq[2];
        #pragma unroll
        for (int r = 0; r < 4; ++r) {
            int ng = n0 + nl0 + i*16 + r;
            float xc = (float)(ng & 63), yc = (float)(ng >> 6);
            float y0 = yib[ng], y1 = yib[HW + ng], y2 = yib[2*HW + ng];
            #pragma unroll
            for (int j = 0; j < 2; ++j) {
                float z = (acc[i][j][r] - bm[j]) * INV_T;
                float e = __expf(z);
                zq[j][r] = (_Float16)z;
                a6[j][0] += e;      a6[j][1] += e*xc; a6[j][2] += e*yc;
                a6[j][3] += e*y0;   a6[j][4] += e*y1; a6[j][5] += e*y2;
            }
        }
        #pragma unroll
        for (int j = 0; j < 2; ++j)
            *(f16x4*)&zh[(size_t)mg[j]*HW + n0 + nl0 + i*16] = zq[j];
    }
    #pragma unroll
    for (int j = 0; j < 2; ++j)
        #pragma unroll
        for (int q = 0; q < 6; ++q) {
            float v = a6[j][q];
            v += __shfl_xor(v, 16);
            v += __shfl_xor(v, 32);
            if (lane < 16) sums6[(wm*128 + wn*32 + j*16 + lane)*6 + q] = v;
        }
    __syncthreads();

    if (tid < 128) {
        int ml = tid;
        float m2 = fmaxf(rowm[ml], rowm[128 + ml]);
        rowp[((size_t)blockIdx.x*7 + 0)*HW + m0 + ml] = m2;
        rmb[(size_t)blockIdx.x*HW + m0 + ml] = m2;
        #pragma unroll
        for (int q = 0; q < 6; ++q)
            rowp[((size_t)blockIdx.x*7 + 1 + q)*HW + m0 + ml] =
                sums6[ml*6 + q] + sums6[(128 + ml)*6 + q];
    } else if (tid < 256) {
        int nl = tid - 128;
        float c2 = fmaxf(fmaxf(colm[nl], colm[128 + nl]),
                         fmaxf(colm[256 + nl], colm[384 + nl]));
        colp[(size_t)blockIdx.y*HW + n0 + nl] = c2;
    }
}

// merged combine: y==0 -> row stats (rsuminv is per-batch slice); y==1 -> col max
__global__ void rowcol_combine_kernel(const float* __restrict__ rowp,
        const float* __restrict__ colp,
        float* __restrict__ rmax, float* __restrict__ rsuminv,
        float* __restrict__ coords, float* __restrict__ attn,
        float* __restrict__ cmax, int b) {
    int idx = blockIdx.x * 256 + threadIdx.x;
    if (blockIdx.y == 0) {
        int m = idx;
        float gm = -3.0e38f;
        for (int t = 0; t < 32; ++t) gm = fmaxf(gm, rowp[((size_t)t*7)*HW + m]);
        float S=0, CX=0, CY=0, A0=0, A1=0, A2=0;
        for (int t = 0; t < 32; ++t) {
            const float* p = rowp + (size_t)t*7*HW + m;
            float wgt = __expf((p[0] - gm) * INV_T);
            S  += p[1*HW] * wgt; CX += p[2*HW] * wgt; CY += p[3*HW] * wgt;
            A0 += p[4*HW] * wgt; A1 += p[5*HW] * wgt; A2 += p[6*HW] * wgt;
        }
        float inv = 1.0f / S;
        rmax[m] = gm; rsuminv[m] = inv;
        coords[((size_t)b*2 + 0)*HW + m] = CX * inv;
        coords[((size_t)b*2 + 1)*HW + m] = CY * inv;
        attn[((size_t)b*HW + m)*3 + 0] = A0 * inv;
        attn[((size_t)b*HW + m)*3 + 1] = A1 * inv;
        attn[((size_t)b*HW + m)*3 + 2] = A2 * inv;
    } else {
        int n = idx;
        float gm = -3.0e38f;
        for (int t = 0; t < 32; ++t) gm = fmaxf(gm, colp[(size_t)t*HW + n]);
        cmax[n] = gm;
    }
}

// y partials: 2-PHASE dbuf. A = exp(z)*corr staged for step k+1 before step k's
// MFMA; B via global_load_lds dbuf. One barrier per K-step.
__global__ __launch_bounds__(512) void gemm_y_kernel(const _Float16* __restrict__ zh,
        const float* __restrict__ rmax, const float* __restrict__ rmb,
        const _Float16* __restrict__ yf16, _Float16* __restrict__ yph, int b) {
    __shared__ __align__(16) char ldsA[2][4096];
    __shared__ __align__(16) char ldsB[2][16384];
    int tid  = threadIdx.x;
    int lane = tid & 63;
    int w = tid >> 6, wm = w >> 2, wn = w & 3;
    int m0 = blockIdx.x * 64;
    int ks = blockIdx.y;
    const _Float16* Yb = yf16 + (size_t)b * NCH * HW;

    int ar = tid >> 3, kc = tid & 7;
    int aslot = kc >> 1, ahalf = kc & 1;
    int aoff = ar*64 + ((aslot ^ ((ar >> 1) & 3)) << 4) + ahalf*8;
    float gm = rmax[m0 + ar];
    const _Float16* zrow = zh + (size_t)(m0 + ar)*HW + kc*4;
    const float* rmbm = rmb + (m0 + ar);

    int o0 = tid*16, o1 = o0 + 8192;
    int br0 = o0 >> 6, bs0 = (o0 >> 4) & 3, bg0 = bs0 ^ ((br0 >> 1) & 3);
    int br1 = o1 >> 6, bs1 = (o1 >> 4) & 3, bg1 = bs1 ^ ((br1 >> 1) & 3);
    size_t gb0 = (size_t)br0*HW + bg0*8;
    size_t gb1 = (size_t)br1*HW + bg1*8;

    int fra = wm*32 + (lane & 15);
    int frb = wn*64 + (lane & 15);
    int kslot = lane >> 4;

    auto STAGEB = [&](int buf, int k0) {
        gload16(Yb + gb0 + k0, &ldsB[buf][o0]);
        gload16(Yb + gb1 + k0, &ldsB[buf][o1]);
    };
    auto WRITEA = [&](int buf, int k0) {
        float cf = __expf((rmbm[(size_t)(k0 >> 7)*HW] - gm) * INV_T);
        f16x4 zv = *(const f16x4*)(zrow + k0);
        f16x4 pk;
        pk[0] = (_Float16)(__expf((float)zv[0]) * cf);
        pk[1] = (_Float16)(__expf((float)zv[1]) * cf);
        pk[2] = (_Float16)(__expf((float)zv[2]) * cf);
        pk[3] = (_Float16)(__expf((float)zv[3]) * cf);
        *(f16x4*)&ldsA[buf][aoff] = pk;
    };

    f32x4 acc[2][4];
    #pragma unroll
    for (int i = 0; i < 2; ++i)
        #pragma unroll
        for (int j = 0; j < 4; ++j) acc[i][j] = (f32x4){0.f, 0.f, 0.f, 0.f};

    int kbase = ks * 1024;
    WRITEA(0, kbase);
    STAGEB(0, kbase);
    __syncthreads();
    int cur = 0;
    for (int s = 0; s < 32; ++s) {
        int k0 = kbase + s*32;
        if (s < 31) {
            STAGEB(cur ^ 1, k0 + 32);
            WRITEA(cur ^ 1, k0 + 32);
        }
        f16x8 af[2], bf[4];
        #pragma unroll
        for (int i = 0; i < 2; ++i) {
            int rowa = fra + i*16;
            af[i] = *(const f16x8*)&ldsA[cur][rowa*64 + ((kslot ^ ((rowa >> 1) & 3)) << 4)];
        }
        #pragma unroll
        for (int j = 0; j < 4; ++j) {
            int rowb = frb + j*16;
            bf[j] = *(const f16x8*)&ldsB[cur][rowb*64 + ((kslot ^ ((rowb >> 1) & 3)) << 4)];
        }
        __builtin_amdgcn_s_setprio(1);
        #pragma unroll
        for (int i = 0; i < 2; ++i)
            #pragma unroll
            for (int j = 0; j < 4; ++j)
                acc[i][j] = __builtin_amdgcn_mfma_f32_16x16x32_f16(af[i], bf[j], acc[i][j], 0, 0, 0);
        __builtin_amdgcn_s_setprio(0);
        __syncthreads();
        cur ^= 1;
    }

    #pragma unroll
    for (int i = 0; i < 2; ++i) {
        int m = m0 + wm*32 + i*16 + (lane >> 4) * 4;
        #pragma unroll
        for (int j = 0; j < 4; ++j) {
            int c = wn*64 + j*16 + (lane & 15);
            f16x4 v;
            #pragma unroll
            for (int r = 0; r < 4; ++r) v[r] = (_Float16)acc[i][j][r];
            *(f16x4*)(yph + ((size_t)ks*NCH + c)*HW + m) = v;
        }
    }
}

// all-batch combine: yph has NB per-batch slices; rsum has NB slices
__global__ void ycombine_kernel(const _Float16* __restrict__ yph, const float* __restrict__ rsum,
                                float* __restrict__ out) {
    int b = blockIdx.y;
    size_t idx = (size_t)blockIdx.x * 256 + threadIdx.x;
    int m = (int)(idx & (HW - 1));
    const _Float16* yb = yph + (size_t)b*4*NCH*HW;
    float s = 0.f;
    #pragma unroll
    for (int k = 0; k < 4; ++k) s += (float)yb[(size_t)k*NCH*HW + idx];
    out[OUT_Y + (size_t)b*NCH*HW + idx] = s * rsum[(size_t)b*HW + m];
}

// cyc partial over row-chunks of 128; reads z f16, corrects by (rmb[i>>7][j] - cmax[i])/T
__global__ __launch_bounds__(256) void cyc_partial_kernel(const _Float16* __restrict__ zh,
        const float* __restrict__ cmax, const float* __restrict__ rmb,
        const float* __restrict__ attn, float* __restrict__ part, int b) {
    __shared__ float at[128*3];
    __shared__ float bmL[2][128];
    int i  = blockIdx.x * 256 + threadIdx.x;
    int j0 = blockIdx.y * 128;
    for (int k = threadIdx.x; k < 384; k += 256)
        at[k] = attn[((size_t)b*HW + j0)*3 + k];
    {
        // bmL[tl][jj] = rmb[col-tile (blockIdx.x*2 + tl)][row j0+jj]
        int k = threadIdx.x;   // 256 threads -> 2 col-tiles x 128 rows
        bmL[k >> 7][k & 127] = rmb[((size_t)(blockIdx.x*2 + (k >> 7)))*HW + j0 + (k & 127)];
    }
    __syncthreads();
    float cm = cmax[i];
    int tl = threadIdx.x >> 7;   // which col-tile this thread's i is in
    float a0=0, a1=0, a2=0, a3=0;
    for (int jj = 0; jj < 128; ++jj) {
        float z = (float)zh[(size_t)(j0+jj)*HW + i];
        float e = __expf(z + (bmL[tl][jj] - cm) * INV_T);
        a0 = fmaf(e, at[jj*3+0], a0);
        a1 = fmaf(e, at[jj*3+1], a1);
        a2 = fmaf(e, at[jj*3+2], a2);
        a3 += e;
    }
    part[((size_t)blockIdx.y*4 + 0)*HW + i] = a0;
    part[((size_t)blockIdx.y*4 + 1)*HW + i] = a1;
    part[((size_t)blockIdx.y*4 + 2)*HW + i] = a2;
    part[((size_t)blockIdx.y*4 + 3)*HW + i] = a3;
}

// all-batch cyc combine
__global__ void cyc_combine_kernel(const float* __restrict__ cycp, float* __restrict__ cyc) {
    int b = blockIdx.z;
    const float* part = cycp + (size_t)b*32*4*HW;
    int i = blockIdx.x * 256 + threadIdx.x;
    int c = blockIdx.y;
    float s = 0.f, den = 0.f;
    for (int k = 0; k < 32; ++k) {
        s   += part[((size_t)k*4 + c)*HW + i];
        den += part[((size_t)k*4 + 3)*HW + i];
    }
    cyc[((size_t)b*3 + c)*HW + i] = s / den;
}

__global__ void flow_kernel(const float* __restrict__ coords, float* __restrict__ out) {
    size_t idx = (size_t)blockIdx.x * 256 + threadIdx.x;
    int x4 = (int)(idx & 255);
    int y4 = (int)((idx >> 8) & 255);
    int ch = (int)((idx >> 16) & 1);
    int b  = (int)(idx >> 17);
    int w = x4 >> 2, h = y4 >> 2;
    int m = h*64 + w;
    float c1 = coords[((size_t)b*2 + ch)*HW + m];
    float c0 = (ch == 0) ? (float)w : (float)h;
    out[OUT_FLOW + idx] = c1 - c0;
}

__global__ void imgout_kernel(const float* __restrict__ attn, const float* __restrict__ cyc,
                              float* __restrict__ out) {
    size_t idx = (size_t)blockIdx.x * 256 + threadIdx.x;
    int x4 = (int)(idx & 255);
    int y4 = (int)((idx >> 8) & 255);
    int rest = (int)(idx >> 16);
    int ch = rest % 3, b = rest / 3;
    int m = (y4 >> 2)*64 + (x4 >> 2);
    out[OUT_IMG  + idx] = attn[((size_t)b*HW + m)*3 + ch];
    out[OUT_CYCO + idx] = cyc[((size_t)b*3 + ch)*HW + m];
}

__global__ void loss_partial_kernel(const float* __restrict__ xf, const float* __restrict__ yf,
                                    const float* __restrict__ means, const float* __restrict__ rnorms,
                                    float* __restrict__ part) {
    __shared__ float red[256];
    size_t base = (size_t)blockIdx.x * 4096;
    float s = 0.f;
    for (int k = 0; k < 16; ++k) {
        size_t id = base + (size_t)k*256 + threadIdx.x;
        int m  = (int)(id & (HW - 1));
        int bc = (int)(id >> 12);
        int b  = bc >> 8;
        float th = (xf[id] - means[bc])          * rnorms[(size_t)b*HW + m];
        float ph = (yf[id] - means[NB*NCH + bc]) * rnorms[(size_t)(NB + b)*HW + m];
        s += fabsf(th - ph);
    }
    red[threadIdx.x] = s; __syncthreads();
    for (int st = 128; st > 0; st >>= 1) {
        if (threadIdx.x < st) red[threadIdx.x] += red[threadIdx.x + st];
        __syncthreads();
    }
    if (threadIdx.x == 0) part[blockIdx.x] = red[0];
}

__global__ void loss_final_kernel(const float* __restrict__ part, float* __restrict__ out) {
    __shared__ float red[256];
    float s = 0.f;
    for (int k = threadIdx.x; k < 1024; k += 256) s += part[k];
    red[threadIdx.x] = s; __syncthreads();
    for (int st = 128; st > 0; st >>= 1) {
        if (threadIdx.x < st) red[threadIdx.x] += red[threadIdx.x + st];
        __syncthreads();
    }
    if (threadIdx.x == 0) out[OUT_LOSS] = red[0] * (1.0f / 4194304.0f);
}

extern "C" void kernel_launch(void* const* d_in, const int* in_sizes, int n_in,
                              void* d_out, int out_size, void* d_ws, size_t ws_size,
                              hipStream_t stream) {
    (void)in_sizes; (void)n_in; (void)out_size; (void)ws_size;
    const float* xf   = (const float*)d_in[0];
    const float* yf   = (const float*)d_in[1];
    const float* yimg = (const float*)d_in[2];
    float* out = (float*)d_out;
    float* ws  = (float*)d_ws;

    _Float16* yf16 = (_Float16*)(ws + OFF_YT);
    float* yi      = ws + OFF_YI;
    float* means   = ws + OFF_MEAN;
    float* rnorms  = ws + OFF_RNORM;
    float* nsqp    = ws + OFF_NSQP;
    _Float16* zh   = (_Float16*)(ws + OFF_F);
    _Float16* yph  = (_Float16*)(ws + OFF_YP);
    float* cycp    = ws + OFF_CYCP;
    float* rowp    = ws + OFF_ROWP;
    float* colp    = ws + OFF_COLP;
    float* rmax    = ws + OFF_RMAX;
    float* rsum    = ws + OFF_RSUM;
    float* cmax    = ws + OFF_CMAX;
    float* rmb     = ws + OFF_RMB;
    float* coords  = ws + OFF_COORD;
    float* attn    = ws + OFF_ATTN;
    float* cyc     = ws + OFF_CYC;
    float* lossp   = ws + OFF_LOSSP;
    _Float16* th = (_Float16*)(ws + OFF_F16);
    _Float16* tl = th + (size_t)HW*NCH;
    _Float16* ph = tl + (size_t)HW*NCH;
    _Float16* pl = ph + (size_t)HW*NCH;

    mean_kernel        <<<dim3(NB*NCH, 2),   256, 0, stream>>>(xf, yf, means);
    ycast_kernel       <<<2048,              256, 0, stream>>>(yf, yf16);
    avgpool_kernel     <<<NB*3*HW/256,       256, 0, stream>>>(yimg, yi);

    for (int b = 0; b < NB; ++b) {
        prep_kernel          <<<dim3(8, 128, 2), 256, 0, stream>>>(xf, yf, means, th, tl, ph, pl,
                                                                   nsqp, b);
        nsq_combine_kernel   <<<dim3(16, 2),     256, 0, stream>>>(nsqp, rnorms, b);
        gemm_f_kernel        <<<dim3(32, 32),    512, 0, stream>>>(th, tl, ph, pl, rnorms, yi,
                                                                   zh, rowp, colp, rmb, b);
        rowcol_combine_kernel<<<dim3(16, 2),     256, 0, stream>>>(rowp, colp, rmax,
                                                                   rsum + (size_t)b*HW,
                                                                   coords, attn, cmax, b);
        gemm_y_kernel        <<<dim3(64, 4),     512, 0, stream>>>(zh, rmax, rmb, yf16,
                                                                   yph + (size_t)b*4*NCH*HW, b);
        cyc_partial_kernel   <<<dim3(16, 32),    256, 0, stream>>>(zh, cmax, rmb, attn,
                                                                   cycp + (size_t)b*32*4*HW, b);
    }

    ycombine_kernel    <<<dim3(NCH*HW/256, NB), 256, 0, stream>>>(yph, rsum, out);
    cyc_combine_kernel <<<dim3(16, 3, NB),      256, 0, stream>>>(cycp, cyc);
    flow_kernel        <<<NB*2*65536/256, 256, 0, stream>>>(coords, out);
    imgout_kernel      <<<NB*3*65536/256, 256, 0, stream>>>(attn, cyc, out);
    loss_partial_kernel<<<1024,           256, 0, stream>>>(xf, yf, means, rnorms, lossp);
    loss_final_kernel  <<<1,              256, 0, stream>>>(lossp, out);
}

// Round 19
// 469.771 us; speedup vs baseline: 1.2617x; 1.0168x over previous
//
#include <hip/hip_runtime.h>
#include <math.h>

#define HW   4096
#define NCH  256
#define NB   4

constexpr float TEMP  = (float)(0.0001 * 5.0);
constexpr float INV_T = 1.0f / TEMP;
constexpr float EPSN  = 2.220446049250313e-16f;

typedef __attribute__((ext_vector_type(8))) _Float16 f16x8;
typedef __attribute__((ext_vector_type(4))) _Float16 f16x4;
typedef __attribute__((ext_vector_type(4))) float    f32x4;

// ---------------- workspace layout (in floats) ----------------
constexpr size_t OFF_YT    = 0;                                 // yf16 uses first 2,097,152 floats
constexpr size_t OFF_PREP1 = OFF_YT    + (size_t)2097152;       // prep buf b=1 (2,097,152)
constexpr size_t OFF_YI    = OFF_YT    + (size_t)NB*HW*NCH;     // = 4,194,304
constexpr size_t OFF_MEAN  = OFF_YI    + (size_t)NB*3*HW;
constexpr size_t OFF_RNORM = OFF_MEAN  + (size_t)2*NB*NCH;
constexpr size_t OFF_NSQP  = OFF_RNORM + (size_t)2*NB*HW;
constexpr size_t OFF_F     = OFF_NSQP  + (size_t)2*NB*8*HW;     // z: HW*HW f16 in LOWER half
constexpr size_t OFF_ZUP   = OFF_F     + (size_t)HW*HW/2;       // upper half of F region
constexpr size_t OFF_CYCP  = OFF_ZUP;                           // NB*32*4*HW = 2,097,152
constexpr size_t OFF_ROWP  = OFF_CYCP  + (size_t)NB*32*4*HW;    // 32*7*HW = 917,504
constexpr size_t OFF_COLP  = OFF_ROWP  + (size_t)32*7*HW;       // 32*HW = 131,072
constexpr size_t OFF_PREP2 = OFF_COLP  + (size_t)32*HW;         // prep buf b=2 (2,097,152)
constexpr size_t OFF_PREP3 = OFF_PREP2 + (size_t)2097152;       // prep buf b=3 (ends 7,340,032 < 8,388,608)
constexpr size_t OFF_YP    = OFF_F     + (size_t)HW*HW;         // yph: NB*4*NCH*HW f16
constexpr size_t OFF_RMAX  = OFF_YP    + (size_t)8*NCH*HW;
constexpr size_t OFF_RSUM  = OFF_RMAX  + HW;                // NB*HW
constexpr size_t OFF_CMAX  = OFF_RSUM  + (size_t)NB*HW;
constexpr size_t OFF_RMB   = OFF_CMAX  + HW;                // [32 ntile][HW m]
constexpr size_t OFF_COORD = OFF_RMB   + (size_t)32*HW;     // NB*2*HW
constexpr size_t OFF_ATTN  = OFF_COORD + (size_t)NB*2*HW;   // NB*HW*3
constexpr size_t OFF_CYC   = OFF_ATTN  + (size_t)NB*HW*3;   // NB*3*HW
constexpr size_t OFF_LOSSP = OFF_CYC   + (size_t)NB*3*HW;   // 1024
constexpr size_t OFF_F16   = OFF_LOSSP + 1024;              // prep buf b=0 (2,097,152)

// ---------------- output layout (floats) ----------------
constexpr size_t OUT_Y    = 0;
constexpr size_t OUT_FLOW = (size_t)NB*NCH*HW;
constexpr size_t OUT_IMG  = OUT_FLOW + (size_t)NB*2*256*256;
constexpr size_t OUT_CYCO = OUT_IMG  + (size_t)NB*3*256*256;
constexpr size_t OUT_LOSS = OUT_CYCO + (size_t)NB*3*256*256;

__device__ __forceinline__ void gload16(const void* g, void* l) {
    __builtin_amdgcn_global_load_lds(
        (const __attribute__((address_space(1))) unsigned int*)g,
        (__attribute__((address_space(3))) unsigned int*)l, 16, 0, 0);
}

__global__ void mean_kernel(const float* __restrict__ xf, const float* __restrict__ yf,
                            float* __restrict__ means) {
    const float* src = (blockIdx.y == 0 ? xf : yf) + (size_t)blockIdx.x * HW;
    float s = 0.f;
    for (int i = threadIdx.x; i < HW; i += 256) s += src[i];
    __shared__ float red[256];
    red[threadIdx.x] = s; __syncthreads();
    for (int st = 128; st > 0; st >>= 1) {
        if (threadIdx.x < st) red[threadIdx.x] += red[threadIdx.x + st];
        __syncthreads();
    }
    if (threadIdx.x == 0) means[blockIdx.y * (NB*NCH) + blockIdx.x] = red[0] * (1.0f / HW);
}

// all-batch combine of nsq partials (b = blockIdx.z)
__global__ void nsq_combine_kernel(const float* __restrict__ part, float* __restrict__ rnorms) {
    int t = blockIdx.y, b = blockIdx.z;
    int m = blockIdx.x * 256 + threadIdx.x;
    const float* p = part + ((size_t)t*NB + b) * 8 * HW + m;
    float s = 0.f;
    for (int k = 0; k < 8; ++k) s += p[(size_t)k * HW];
    rnorms[((size_t)t*NB + b) * HW + m] = 1.0f / (sqrtf(s) + EPSN);
}

__global__ void ycast_kernel(const float* __restrict__ yf, _Float16* __restrict__ yf16) {
    size_t i = ((size_t)blockIdx.x * 256 + threadIdx.x) * 8;
    const float4* s = (const float4*)(yf + i);
    float4 v0 = s[0], v1 = s[1];
    f16x8 o;
    o[0]=(_Float16)v0.x; o[1]=(_Float16)v0.y; o[2]=(_Float16)v0.z; o[3]=(_Float16)v0.w;
    o[4]=(_Float16)v1.x; o[5]=(_Float16)v1.y; o[6]=(_Float16)v1.z; o[7]=(_Float16)v1.w;
    *(f16x8*)(yf16 + i) = o;
}

__global__ void prep_kernel(const float* __restrict__ xf, const float* __restrict__ yf,
                            const float* __restrict__ means,
                            _Float16* __restrict__ th, _Float16* __restrict__ tl,
                            _Float16* __restrict__ ph, _Float16* __restrict__ pl,
                            float* __restrict__ nsqp, int b) {
    __shared__ float tile[32][33];
    __shared__ float sqr[8][33];
    int t = blockIdx.z;
    int c0 = blockIdx.x * 32, m0 = blockIdx.y * 32;
    const float* src = (t == 0 ? xf : yf) + (size_t)b * NCH * HW;
    const float* mn  = means + t * (NB*NCH) + b * NCH;
    int tx = threadIdx.x & 31, ty = threadIdx.x >> 5;
    float sq = 0.f;
    for (int i = ty; i < 32; i += 8) {
        float v = src[(size_t)(c0 + i) * HW + m0 + tx] - mn[c0 + i];
        tile[i][tx] = v;
        sq += v * v;
    }
    sqr[ty][tx] = sq;
    __syncthreads();
    _Float16* H = (t == 0 ? th : ph);
    _Float16* L = (t == 0 ? tl : pl);
    for (int i = ty; i < 32; i += 8) {
        float v = tile[tx][i];
        _Float16 h = (_Float16)v;
        _Float16 l = (_Float16)(v - (float)h);
        H[(size_t)(m0 + i)*NCH + c0 + tx] = h;
        L[(size_t)(m0 + i)*NCH + c0 + tx] = l;
    }
    if (ty == 0) {
        float s = 0.f;
        #pragma unroll
        for (int k = 0; k < 8; ++k) s += sqr[k][tx];
        nsqp[(((size_t)t*NB + b) * 8 + blockIdx.x) * HW + m0 + tx] = s;
    }
}

__global__ void avgpool_kernel(const float* __restrict__ yimg, float* __restrict__ yi) {
    size_t idx = (size_t)blockIdx.x * 256 + threadIdx.x;
    int m  = (int)(idx & (HW - 1));
    int bc = (int)(idx >> 12);
    int h = m >> 6, w = m & 63;
    const float* p = yimg + (size_t)bc * 65536 + (size_t)(h*4) * 256 + w*4;
    float s = 0.f;
    #pragma unroll
    for (int dy = 0; dy < 4; ++dy) {
        #pragma unroll
        for (int dx = 0; dx < 4; ++dx) s += p[dy*256 + dx];
    }
    yi[idx] = s * (1.0f/16.0f);
}

// f^T accumulator GEMM (R18 structure + XCD-patch swizzle): 128x128 tile, 8 waves,
// BK=32, 2-phase dbuf. z f16 out; row stats + col max + rmb.
__global__ __launch_bounds__(512) void gemm_f_kernel(
        const _Float16* __restrict__ th, const _Float16* __restrict__ tl,
        const _Float16* __restrict__ ph, const _Float16* __restrict__ pl,
        const float* __restrict__ rnorms, const float* __restrict__ yi,
        _Float16* __restrict__ zh, float* __restrict__ rowp, float* __restrict__ colp,
        float* __restrict__ rmb, int b) {
    __shared__ char lds[2][4][8192];
    int tid  = threadIdx.x;
    int lane = tid & 63;
    int w = tid >> 6;
    int wm = w >> 2;       // 0..1  n-half (A/phi)
    int wn = w & 3;        // 0..3  m-quarter (B/theta)

    // XCD-aware bijective swizzle: grid 32x32=1024, 8 XCDs -> 8(bx)x16(by) patch each
    int lid = blockIdx.y * 32 + blockIdx.x;
    int xcd = lid & 7, kk = lid >> 3;
    int bx = (xcd & 3) * 8 + (kk & 7);    // n-tile
    int by = (xcd >> 2) * 16 + (kk >> 3); // m-tile
    int m0 = by * 128, n0 = bx * 128;

    int o0 = tid * 16;
    int r0 = o0 >> 6, s0 = (o0 >> 4) & 3, g0 = s0 ^ ((r0 >> 1) & 3);
    size_t ga0 = (size_t)(n0 + r0)*NCH + g0*8;   // phi row (n)
    size_t gb0 = (size_t)(m0 + r0)*NCH + g0*8;   // theta row (m)

    int fra = wm*64 + (lane & 15);
    int frb = wn*32 + (lane & 15);
    int ks  = lane >> 4;

    auto STAGE = [&](int buf, int k0) {
        gload16(ph + ga0 + k0, &lds[buf][0][o0]);
        gload16(pl + ga0 + k0, &lds[buf][1][o0]);
        gload16(th + gb0 + k0, &lds[buf][2][o0]);
        gload16(tl + gb0 + k0, &lds[buf][3][o0]);
    };

    f32x4 acc[4][2];
    #pragma unroll
    for (int i = 0; i < 4; ++i)
        #pragma unroll
        for (int j = 0; j < 2; ++j) acc[i][j] = (f32x4){0.f, 0.f, 0.f, 0.f};

    STAGE(0, 0);
    __syncthreads();
    int cur = 0;
    for (int kt = 0; kt < 8; ++kt) {
        if (kt < 7) STAGE(cur ^ 1, (kt + 1) * 32);

        f16x8 ah[4], al[4], bh[2], bl[2];
        #pragma unroll
        for (int i = 0; i < 4; ++i) {
            int rowa = fra + i*16;
            int offa = rowa*64 + ((ks ^ ((rowa >> 1) & 3)) << 4);
            ah[i] = *(const f16x8*)&lds[cur][0][offa];
            al[i] = *(const f16x8*)&lds[cur][1][offa];
        }
        #pragma unroll
        for (int j = 0; j < 2; ++j) {
            int rowb = frb + j*16;
            int offb = rowb*64 + ((ks ^ ((rowb >> 1) & 3)) << 4);
            bh[j] = *(const f16x8*)&lds[cur][2][offb];
            bl[j] = *(const f16x8*)&lds[cur][3][offb];
        }
        __builtin_amdgcn_s_setprio(1);
        #pragma unroll
        for (int i = 0; i < 4; ++i)
            #pragma unroll
            for (int j = 0; j < 2; ++j) {
                acc[i][j] = __builtin_amdgcn_mfma_f32_16x16x32_f16(ah[i], bh[j], acc[i][j], 0, 0, 0);
                acc[i][j] = __builtin_amdgcn_mfma_f32_16x16x32_f16(ah[i], bl[j], acc[i][j], 0, 0, 0);
                acc[i][j] = __builtin_amdgcn_mfma_f32_16x16x32_f16(al[i], bh[j], acc[i][j], 0, 0, 0);
            }
        __builtin_amdgcn_s_setprio(0);
        __syncthreads();
        cur ^= 1;
    }

    // ---- scale in place: f[m][n] = accT * rnx[m] * rny[n] ----
    const float* rnx = rnorms + (size_t)b * HW;
    const float* rny = rnorms + (size_t)(NB + b) * HW;
    int mg[2];  float rxv[2];
    #pragma unroll
    for (int j = 0; j < 2; ++j) {
        mg[j] = m0 + wn*32 + j*16 + (lane & 15);
        rxv[j] = rnx[mg[j]];
    }
    int nl0 = wm*64 + (lane >> 4)*4;
    #pragma unroll
    for (int i = 0; i < 4; ++i)
        #pragma unroll
        for (int r = 0; r < 4; ++r) {
            float ry = rny[n0 + nl0 + i*16 + r];
            #pragma unroll
            for (int j = 0; j < 2; ++j) acc[i][j][r] *= rxv[j] * ry;
        }

    // ---- stats ----
    float* S     = (float*)&lds[0][0][0];
    float* rowm  = S;          // [2 wm][128 m]
    float* sums6 = S + 256;    // [2 wm][128 m][6]
    float* colm  = S + 1792;   // [4 wn][128 n]

    #pragma unroll
    for (int j = 0; j < 2; ++j) {
        float v = acc[0][j][0];
        #pragma unroll
        for (int i = 0; i < 4; ++i)
            #pragma unroll
            for (int r = 0; r < 4; ++r) v = fmaxf(v, acc[i][j][r]);
        v = fmaxf(v, __shfl_xor(v, 16));
        v = fmaxf(v, __shfl_xor(v, 32));
        if (lane < 16) rowm[wm*128 + wn*32 + j*16 + lane] = v;
    }
    #pragma unroll
    for (int i = 0; i < 4; ++i)
        #pragma unroll
        for (int r = 0; r < 4; ++r) {
            float v = fmaxf(acc[i][0][r], acc[i][1][r]);
            #pragma unroll
            for (int d = 1; d < 16; d <<= 1) v = fmaxf(v, __shfl_xor(v, d));
            if ((lane & 15) == 0) colm[wn*128 + nl0 + i*16 + r] = v;
        }
    __syncthreads();

    float bm[2];
    #pragma unroll
    for (int j = 0; j < 2; ++j) {
        int ml = wn*32 + j*16 + (lane & 15);
        bm[j] = fmaxf(rowm[ml], rowm[128 + ml]);
    }
    float a6[2][6];
    #pragma unroll
    for (int j = 0; j < 2; ++j)
        #pragma unroll
        for (int q = 0; q < 6; ++q) a6[j][q] = 0.f;
    const float* yib = yi + (size_t)b * 3 * HW;
    #pragma unroll
    for (int i = 0; i < 4; ++i) {
        f16x4 zq[2];
        #pragma unroll
        for (int r = 0; r < 4; ++r) {
            int ng = n0 + nl0 + i*16 + r;
            float xc = (float)(ng & 63), yc = (float)(ng >> 6);
            float y0 = yib[ng], y1 = yib[HW + ng], y2 = yib[2*HW + ng];
            #pragma unroll
            for (int j = 0; j < 2; ++j) {
                float z = (acc[i][j][r] - bm[j]) * INV_T;
                float e = __expf(z);
                zq[j][r] = (_Float16)z;
                a6[j][0] += e;      a6[j][1] += e*xc; a6[j][2] += e*yc;
                a6[j][3] += e*y0;   a6[j][4] += e*y1; a6[j][5] += e*y2;
            }
        }
        #pragma unroll
        for (int j = 0; j < 2; ++j)
            *(f16x4*)&zh[(size_t)mg[j]*HW + n0 + nl0 + i*16] = zq[j];
    }
    #pragma unroll
    for (int j = 0; j < 2; ++j)
        #pragma unroll
        for (int q = 0; q < 6; ++q) {
            float v = a6[j][q];
            v += __shfl_xor(v, 16);
            v += __shfl_xor(v, 32);
            if (lane < 16) sums6[(wm*128 + wn*32 + j*16 + lane)*6 + q] = v;
        }
    __syncthreads();

    if (tid < 128) {
        int ml = tid;
        float m2 = fmaxf(rowm[ml], rowm[128 + ml]);
        rowp[((size_t)bx*7 + 0)*HW + m0 + ml] = m2;
        rmb[(size_t)bx*HW + m0 + ml] = m2;
        #pragma unroll
        for (int q = 0; q < 6; ++q)
            rowp[((size_t)bx*7 + 1 + q)*HW + m0 + ml] =
                sums6[ml*6 + q] + sums6[(128 + ml)*6 + q];
    } else if (tid < 256) {
        int nl = tid - 128;
        float c2 = fmaxf(fmaxf(colm[nl], colm[128 + nl]),
                         fmaxf(colm[256 + nl], colm[384 + nl]));
        colp[(size_t)by*HW + n0 + nl] = c2;
    }
}

// merged combine: y==0 -> row stats (rsuminv = per-batch slice); y==1 -> col max
__global__ void rowcol_combine_kernel(const float* __restrict__ rowp,
        const float* __restrict__ colp,
        float* __restrict__ rmax, float* __restrict__ rsuminv,
        float* __restrict__ coords, float* __restrict__ attn,
        float* __restrict__ cmax, int b) {
    int idx = blockIdx.x * 256 + threadIdx.x;
    if (blockIdx.y == 0) {
        int m = idx;
        float gm = -3.0e38f;
        for (int t = 0; t < 32; ++t) gm = fmaxf(gm, rowp[((size_t)t*7)*HW + m]);
        float S=0, CX=0, CY=0, A0=0, A1=0, A2=0;
        for (int t = 0; t < 32; ++t) {
            const float* p = rowp + (size_t)t*7*HW + m;
            float wgt = __expf((p[0] - gm) * INV_T);
            S  += p[1*HW] * wgt; CX += p[2*HW] * wgt; CY += p[3*HW] * wgt;
            A0 += p[4*HW] * wgt; A1 += p[5*HW] * wgt; A2 += p[6*HW] * wgt;
        }
        float inv = 1.0f / S;
        rmax[m] = gm; rsuminv[m] = inv;
        coords[((size_t)b*2 + 0)*HW + m] = CX * inv;
        coords[((size_t)b*2 + 1)*HW + m] = CY * inv;
        attn[((size_t)b*HW + m)*3 + 0] = A0 * inv;
        attn[((size_t)b*HW + m)*3 + 1] = A1 * inv;
        attn[((size_t)b*HW + m)*3 + 2] = A2 * inv;
    } else {
        int n = idx;
        float gm = -3.0e38f;
        for (int t = 0; t < 32; ++t) gm = fmaxf(gm, colp[(size_t)t*HW + n]);
        cmax[n] = gm;
    }
}

// y partials: 2-phase dbuf + XCD swizzle (same-ks m-tiles grouped per XCD)
__global__ __launch_bounds__(512) void gemm_y_kernel(const _Float16* __restrict__ zh,
        const float* __restrict__ rmax, const float* __restrict__ rmb,
        const _Float16* __restrict__ yf16, _Float16* __restrict__ yph, int b) {
    __shared__ __align__(16) char ldsA[2][4096];
    __shared__ __align__(16) char ldsB[2][16384];
    int tid  = threadIdx.x;
    int lane = tid & 63;
    int w = tid >> 6, wm = w >> 2, wn = w & 3;

    // XCD swizzle: grid (64,4)=256; swz chunks of 32 per XCD
    int lid = blockIdx.y * 64 + blockIdx.x;
    int swz = (lid & 7) * 32 + (lid >> 3);
    int mtile = swz & 63, ks = swz >> 6;
    int m0 = mtile * 64;
    const _Float16* Yb = yf16 + (size_t)b * NCH * HW;

    int ar = tid >> 3, kc = tid & 7;
    int aslot = kc >> 1, ahalf = kc & 1;
    int aoff = ar*64 + ((aslot ^ ((ar >> 1) & 3)) << 4) + ahalf*8;
    float gm = rmax[m0 + ar];
    const _Float16* zrow = zh + (size_t)(m0 + ar)*HW + kc*4;
    const float* rmbm = rmb + (m0 + ar);

    int o0 = tid*16, o1 = o0 + 8192;
    int br0 = o0 >> 6, bs0 = (o0 >> 4) & 3, bg0 = bs0 ^ ((br0 >> 1) & 3);
    int br1 = o1 >> 6, bs1 = (o1 >> 4) & 3, bg1 = bs1 ^ ((br1 >> 1) & 3);
    size_t gb0 = (size_t)br0*HW + bg0*8;
    size_t gb1 = (size_t)br1*HW + bg1*8;

    int fra = wm*32 + (lane & 15);
    int frb = wn*64 + (lane & 15);
    int kslot = lane >> 4;

    auto STAGEB = [&](int buf, int k0) {
        gload16(Yb + gb0 + k0, &ldsB[buf][o0]);
        gload16(Yb + gb1 + k0, &ldsB[buf][o1]);
    };
    auto WRITEA = [&](int buf, int k0) {
        float cf = __expf((rmbm[(size_t)(k0 >> 7)*HW] - gm) * INV_T);
        f16x4 zv = *(const f16x4*)(zrow + k0);
        f16x4 pk;
        pk[0] = (_Float16)(__expf((float)zv[0]) * cf);
        pk[1] = (_Float16)(__expf((float)zv[1]) * cf);
        pk[2] = (_Float16)(__expf((float)zv[2]) * cf);
        pk[3] = (_Float16)(__expf((float)zv[3]) * cf);
        *(f16x4*)&ldsA[buf][aoff] = pk;
    };

    f32x4 acc[2][4];
    #pragma unroll
    for (int i = 0; i < 2; ++i)
        #pragma unroll
        for (int j = 0; j < 4; ++j) acc[i][j] = (f32x4){0.f, 0.f, 0.f, 0.f};

    int kbase = ks * 1024;
    WRITEA(0, kbase);
    STAGEB(0, kbase);
    __syncthreads();
    int cur = 0;
    for (int s = 0; s < 32; ++s) {
        int k0 = kbase + s*32;
        if (s < 31) {
            STAGEB(cur ^ 1, k0 + 32);
            WRITEA(cur ^ 1, k0 + 32);
        }
        f16x8 af[2], bf[4];
        #pragma unroll
        for (int i = 0; i < 2; ++i) {
            int rowa = fra + i*16;
            af[i] = *(const f16x8*)&ldsA[cur][rowa*64 + ((kslot ^ ((rowa >> 1) & 3)) << 4)];
        }
        #pragma unroll
        for (int j = 0; j < 4; ++j) {
            int rowb = frb + j*16;
            bf[j] = *(const f16x8*)&ldsB[cur][rowb*64 + ((kslot ^ ((rowb >> 1) & 3)) << 4)];
        }
        __builtin_amdgcn_s_setprio(1);
        #pragma unroll
        for (int i = 0; i < 2; ++i)
            #pragma unroll
            for (int j = 0; j < 4; ++j)
                acc[i][j] = __builtin_amdgcn_mfma_f32_16x16x32_f16(af[i], bf[j], acc[i][j], 0, 0, 0);
        __builtin_amdgcn_s_setprio(0);
        __syncthreads();
        cur ^= 1;
    }

    #pragma unroll
    for (int i = 0; i < 2; ++i) {
        int m = m0 + wm*32 + i*16 + (lane >> 4) * 4;
        #pragma unroll
        for (int j = 0; j < 4; ++j) {
            int c = wn*64 + j*16 + (lane & 15);
            f16x4 v;
            #pragma unroll
            for (int r = 0; r < 4; ++r) v[r] = (_Float16)acc[i][j][r];
            *(f16x4*)(yph + ((size_t)ks*NCH + c)*HW + m) = v;
        }
    }
}

// all-batch combine: yph has NB per-batch slices; rsum has NB slices
__global__ void ycombine_kernel(const _Float16* __restrict__ yph, const float* __restrict__ rsum,
                                float* __restrict__ out) {
    int b = blockIdx.y;
    size_t idx = (size_t)blockIdx.x * 256 + threadIdx.x;
    int m = (int)(idx & (HW - 1));
    const _Float16* yb = yph + (size_t)b*4*NCH*HW;
    float s = 0.f;
    #pragma unroll
    for (int k = 0; k < 4; ++k) s += (float)yb[(size_t)k*NCH*HW + idx];
    out[OUT_Y + (size_t)b*NCH*HW + idx] = s * rsum[(size_t)b*HW + m];
}

// cyc partial over row-chunks of 128; corrects by (rmb[col-tile][row j] - cmax[i])/T
__global__ __launch_bounds__(256) void cyc_partial_kernel(const _Float16* __restrict__ zh,
        const float* __restrict__ cmax, const float* __restrict__ rmb,
        const float* __restrict__ attn, float* __restrict__ part, int b) {
    __shared__ float at[128*3];
    __shared__ float bmL[2][128];
    int i  = blockIdx.x * 256 + threadIdx.x;
    int j0 = blockIdx.y * 128;
    for (int k = threadIdx.x; k < 384; k += 256)
        at[k] = attn[((size_t)b*HW + j0)*3 + k];
    {
        int k = threadIdx.x;   // 256 threads -> 2 col-tiles x 128 rows
        bmL[k >> 7][k & 127] = rmb[((size_t)(blockIdx.x*2 + (k >> 7)))*HW + j0 + (k & 127)];
    }
    __syncthreads();
    float cm = cmax[i];
    int tl = threadIdx.x >> 7;
    float a0=0, a1=0, a2=0, a3=0;
    for (int jj = 0; jj < 128; ++jj) {
        float z = (float)zh[(size_t)(j0+jj)*HW + i];
        float e = __expf(z + (bmL[tl][jj] - cm) * INV_T);
        a0 = fmaf(e, at[jj*3+0], a0);
        a1 = fmaf(e, at[jj*3+1], a1);
        a2 = fmaf(e, at[jj*3+2], a2);
        a3 += e;
    }
    part[((size_t)blockIdx.y*4 + 0)*HW + i] = a0;
    part[((size_t)blockIdx.y*4 + 1)*HW + i] = a1;
    part[((size_t)blockIdx.y*4 + 2)*HW + i] = a2;
    part[((size_t)blockIdx.y*4 + 3)*HW + i] = a3;
}

// all-batch cyc combine
__global__ void cyc_combine_kernel(const float* __restrict__ cycp, float* __restrict__ cyc) {
    int b = blockIdx.z;
    const float* part = cycp + (size_t)b*32*4*HW;
    int i = blockIdx.x * 256 + threadIdx.x;
    int c = blockIdx.y;
    float s = 0.f, den = 0.f;
    for (int k = 0; k < 32; ++k) {
        s   += part[((size_t)k*4 + c)*HW + i];
        den += part[((size_t)k*4 + 3)*HW + i];
    }
    cyc[((size_t)b*3 + c)*HW + i] = s / den;
}

__global__ void flow_kernel(const float* __restrict__ coords, float* __restrict__ out) {
    size_t idx = (size_t)blockIdx.x * 256 + threadIdx.x;
    int x4 = (int)(idx & 255);
    int y4 = (int)((idx >> 8) & 255);
    int ch = (int)((idx >> 16) & 1);
    int b  = (int)(idx >> 17);
    int w = x4 >> 2, h = y4 >> 2;
    int m = h*64 + w;
    float c1 = coords[((size_t)b*2 + ch)*HW + m];
    float c0 = (ch == 0) ? (float)w : (float)h;
    out[OUT_FLOW + idx] = c1 - c0;
}

__global__ void imgout_kernel(const float* __restrict__ attn, const float* __restrict__ cyc,
                              float* __restrict__ out) {
    size_t idx = (size_t)blockIdx.x * 256 + threadIdx.x;
    int x4 = (int)(idx & 255);
    int y4 = (int)((idx >> 8) & 255);
    int rest = (int)(idx >> 16);
    int ch = rest % 3, b = rest / 3;
    int m = (y4 >> 2)*64 + (x4 >> 2);
    out[OUT_IMG  + idx] = attn[((size_t)b*HW + m)*3 + ch];
    out[OUT_CYCO + idx] = cyc[((size_t)b*3 + ch)*HW + m];
}

__global__ void loss_partial_kernel(const float* __restrict__ xf, const float* __restrict__ yf,
                                    const float* __restrict__ means, const float* __restrict__ rnorms,
                                    float* __restrict__ part) {
    __shared__ float red[256];
    size_t base = (size_t)blockIdx.x * 4096;
    float s = 0.f;
    for (int k = 0; k < 16; ++k) {
        size_t id = base + (size_t)k*256 + threadIdx.x;
        int m  = (int)(id & (HW - 1));
        int bc = (int)(id >> 12);
        int b  = bc >> 8;
        float th = (xf[id] - means[bc])          * rnorms[(size_t)b*HW + m];
        float ph = (yf[id] - means[NB*NCH + bc]) * rnorms[(size_t)(NB + b)*HW + m];
        s += fabsf(th - ph);
    }
    red[threadIdx.x] = s; __syncthreads();
    for (int st = 128; st > 0; st >>= 1) {
        if (threadIdx.x < st) red[threadIdx.x] += red[threadIdx.x + st];
        __syncthreads();
    }
    if (threadIdx.x == 0) part[blockIdx.x] = red[0];
}

__global__ void loss_final_kernel(const float* __restrict__ part, float* __restrict__ out) {
    __shared__ float red[256];
    float s = 0.f;
    for (int k = threadIdx.x; k < 1024; k += 256) s += part[k];
    red[threadIdx.x] = s; __syncthreads();
    for (int st = 128; st > 0; st >>= 1) {
        if (threadIdx.x < st) red[threadIdx.x] += red[threadIdx.x + st];
        __syncthreads();
    }
    if (threadIdx.x == 0) out[OUT_LOSS] = red[0] * (1.0f / 4194304.0f);
}

extern "C" void kernel_launch(void* const* d_in, const int* in_sizes, int n_in,
                              void* d_out, int out_size, void* d_ws, size_t ws_size,
                              hipStream_t stream) {
    (void)in_sizes; (void)n_in; (void)out_size; (void)ws_size;
    const float* xf   = (const float*)d_in[0];
    const float* yf   = (const float*)d_in[1];
    const float* yimg = (const float*)d_in[2];
    float* out = (float*)d_out;
    float* ws  = (float*)d_ws;

    _Float16* yf16 = (_Float16*)(ws + OFF_YT);
    float* yi      = ws + OFF_YI;
    float* means   = ws + OFF_MEAN;
    float* rnorms  = ws + OFF_RNORM;
    float* nsqp    = ws + OFF_NSQP;
    _Float16* zh   = (_Float16*)(ws + OFF_F);
    _Float16* yph  = (_Float16*)(ws + OFF_YP);
    float* cycp    = ws + OFF_CYCP;
    float* rowp    = ws + OFF_ROWP;
    float* colp    = ws + OFF_COLP;
    float* rmax    = ws + OFF_RMAX;
    float* rsum    = ws + OFF_RSUM;
    float* cmax    = ws + OFF_CMAX;
    float* rmb     = ws + OFF_RMB;
    float* coords  = ws + OFF_COORD;
    float* attn    = ws + OFF_ATTN;
    float* cyc     = ws + OFF_CYC;
    float* lossp   = ws + OFF_LOSSP;

    // per-batch prep buffers (th/tl/ph/pl, each HW*NCH f16)
    const size_t prep_off[NB] = { OFF_F16, OFF_PREP1, OFF_PREP2, OFF_PREP3 };

    mean_kernel        <<<dim3(NB*NCH, 2),   256, 0, stream>>>(xf, yf, means);
    ycast_kernel       <<<2048,              256, 0, stream>>>(yf, yf16);
    avgpool_kernel     <<<NB*3*HW/256,       256, 0, stream>>>(yimg, yi);

    // all-batch prep upfront
    for (int b = 0; b < NB; ++b) {
        _Float16* th = (_Float16*)(ws + prep_off[b]);
        _Float16* tl = th + (size_t)HW*NCH;
        _Float16* ph = tl + (size_t)HW*NCH;
        _Float16* pl = ph + (size_t)HW*NCH;
        prep_kernel    <<<dim3(8, 128, 2), 256, 0, stream>>>(xf, yf, means, th, tl, ph, pl,
                                                             nsqp, b);
    }
    nsq_combine_kernel <<<dim3(16, 2, NB), 256, 0, stream>>>(nsqp, rnorms);

    for (int b = 0; b < NB; ++b) {
        _Float16* th = (_Float16*)(ws + prep_off[b]);
        _Float16* tl = th + (size_t)HW*NCH;
        _Float16* ph = tl + (size_t)HW*NCH;
        _Float16* pl = ph + (size_t)HW*NCH;
        gemm_f_kernel        <<<dim3(32, 32),    512, 0, stream>>>(th, tl, ph, pl, rnorms, yi,
                                                                   zh, rowp, colp, rmb, b);
        rowcol_combine_kernel<<<dim3(16, 2),     256, 0, stream>>>(rowp, colp, rmax,
                                                                   rsum + (size_t)b*HW,
                                                                   coords, attn, cmax, b);
        gemm_y_kernel        <<<dim3(64, 4),     512, 0, stream>>>(zh, rmax, rmb, yf16,
                                                                   yph + (size_t)b*4*NCH*HW, b);
        cyc_partial_kernel   <<<dim3(16, 32),    256, 0, stream>>>(zh, cmax, rmb, attn,
                                                                   cycp + (size_t)b*32*4*HW, b);
    }

    ycombine_kernel    <<<dim3(NCH*HW/256, NB), 256, 0, stream>>>(yph, rsum, out);
    cyc_combine_kernel <<<dim3(16, 3, NB),      256, 0, stream>>>(cycp, cyc);
    flow_kernel        <<<NB*2*65536/256, 256, 0, stream>>>(coords, out);
    imgout_kernel      <<<NB*3*65536/256, 256, 0, stream>>>(attn, cyc, out);
    loss_partial_kernel<<<1024,           256, 0, stream>>>(xf, yf, means, rnorms, lossp);
    loss_final_kernel  <<<1,              256, 0, stream>>>(lossp, out);
}